// Round 1
// baseline (1048.085 us; speedup 1.0000x reference)
//
#include <hip/hip_runtime.h>
#include <math.h>

#define B_ 2
#define N_ 2048
#define DIN 1024
#define DOUT 1024
#define H_ 16
#define HD_ 64
#define M_ (B_ * N_)          // 4096 rows
#define SCALE 0.125f          // 1/sqrt(64)

// ---------------------------------------------------------------------------
// Kernel 1: fused QKV projection.  C = x @ {Wq|Wk|Wv}, written to q/k/v in
// [B, H, N, HD] layout.  64x64 tile, BK=16, 256 threads, 4x4 micro-tile.
// grid = (M/64, 3*DOUT/64) = (64, 48)
// ---------------------------------------------------------------------------
__global__ __launch_bounds__(256) void qkv_gemm(
    const float* __restrict__ x,
    const float* __restrict__ Wq, const float* __restrict__ Wk,
    const float* __restrict__ Wv,
    float* __restrict__ q, float* __restrict__ k, float* __restrict__ v)
{
    __shared__ float As[64][17];   // +1 pad breaks bank aliasing on column reads
    __shared__ float Bs[16][64];

    const int tid = threadIdx.x;
    const int tx = tid & 15, ty = tid >> 4;
    const int tileM = blockIdx.x * 64;
    const int ctile = blockIdx.y * 64;         // 0..3071
    const int w = ctile >> 10;                 // 0:Q 1:K 2:V (tile never spans)
    const int cw0 = ctile & 1023;              // col within selected W

    const float* W = (w == 0) ? Wq : ((w == 1) ? Wk : Wv);
    float* out = (w == 0) ? q : ((w == 1) ? k : v);

    float acc[4][4] = {};

    const int la_r = tid >> 2;                 // 0..63
    const int la_k = (tid & 3) << 2;           // 0,4,8,12
    const int lb_k = tid >> 4;                 // 0..15
    const int lb_c = (tid & 15) << 2;          // 0..60

    for (int k0 = 0; k0 < DIN; k0 += 16) {
        float4 a4 = *(const float4*)&x[(size_t)(tileM + la_r) * DIN + k0 + la_k];
        As[la_r][la_k + 0] = a4.x; As[la_r][la_k + 1] = a4.y;
        As[la_r][la_k + 2] = a4.z; As[la_r][la_k + 3] = a4.w;
        *(float4*)&Bs[lb_k][lb_c] =
            *(const float4*)&W[(size_t)(k0 + lb_k) * DOUT + cw0 + lb_c];
        __syncthreads();
        #pragma unroll
        for (int kk = 0; kk < 16; ++kk) {
            const float a0 = As[ty * 4 + 0][kk];
            const float a1 = As[ty * 4 + 1][kk];
            const float a2 = As[ty * 4 + 2][kk];
            const float a3 = As[ty * 4 + 3][kk];
            const float4 b4 = *(const float4*)&Bs[kk][tx << 2];
            acc[0][0] += a0 * b4.x; acc[0][1] += a0 * b4.y;
            acc[0][2] += a0 * b4.z; acc[0][3] += a0 * b4.w;
            acc[1][0] += a1 * b4.x; acc[1][1] += a1 * b4.y;
            acc[1][2] += a1 * b4.z; acc[1][3] += a1 * b4.w;
            acc[2][0] += a2 * b4.x; acc[2][1] += a2 * b4.y;
            acc[2][2] += a2 * b4.z; acc[2][3] += a2 * b4.w;
            acc[3][0] += a3 * b4.x; acc[3][1] += a3 * b4.y;
            acc[3][2] += a3 * b4.z; acc[3][3] += a3 * b4.w;
        }
        __syncthreads();
    }

    // scatter to [B, H, N, HD]
    #pragma unroll
    for (int i = 0; i < 4; ++i) {
        const int r = tileM + ty * 4 + i;
        const int b = r >> 11;                 // r / N_
        const int n = r & (N_ - 1);
        const int cw = cw0 + (tx << 2);        // 4 cols, same head (64 | cw0)
        const int h = cw >> 6;
        const int hd = cw & 63;
        float* dst = &out[((size_t)(b * H_ + h) * N_ + n) * HD_ + hd];
        *(float4*)dst = make_float4(acc[i][0], acc[i][1], acc[i][2], acc[i][3]);
    }
}

// ---------------------------------------------------------------------------
// Kernel 2: causal flash attention (fp32).  One block per (bh, 64-query tile).
// K and V time-share one LDS buffer.  256 threads; thread (qg2 = tid>>4,
// jt = tid&15) owns a 4x4 score tile {q = qg2*4+i, j = jt+16c} and a 4x4
// output tile {q = qg2*4+i, d = jt*4+dd}.  Row softmax reduced over the 16
// jt-lanes via shfl_xor.  grid = (N/64, B*H) = (32, 32)
// ---------------------------------------------------------------------------
__global__ __launch_bounds__(256) void attn_fwd(
    const float* __restrict__ q, const float* __restrict__ k,
    const float* __restrict__ v, float* __restrict__ ctx)
{
    __shared__ float Qs[64][68];
    __shared__ float KVs[64][68];
    __shared__ float Ps[64][68];

    const int tid = threadIdx.x;
    const int qg2 = tid >> 4;     // 0..15
    const int jt = tid & 15;      // 0..15
    const int qb = blockIdx.x;    // query tile
    const int bh = blockIdx.y;    // b*H + h

    const float* qbase = q + (size_t)bh * N_ * HD_;
    const float* kbase = k + (size_t)bh * N_ * HD_;
    const float* vbase = v + (size_t)bh * N_ * HD_;

    // load Q tile (64x64 floats = 1024 float4, 4 per thread)
    {
        const float* src = qbase + (size_t)qb * 64 * HD_;
        #pragma unroll
        for (int it = 0; it < 4; ++it) {
            const int fi = tid + it * 256;
            const int r = fi >> 4, c4 = (fi & 15) << 2;
            *(float4*)&Qs[r][c4] = *(const float4*)&src[r * HD_ + c4];
        }
    }

    float m[4], l[4], O[4][4];
    #pragma unroll
    for (int i = 0; i < 4; ++i) {
        m[i] = -INFINITY; l[i] = 0.f;
        O[i][0] = O[i][1] = O[i][2] = O[i][3] = 0.f;
    }

    for (int kb = 0; kb <= qb; ++kb) {
        __syncthreads();   // prev V reads done / Q visible on first iter
        {   // load K tile
            const float* src = kbase + (size_t)kb * 64 * HD_;
            #pragma unroll
            for (int it = 0; it < 4; ++it) {
                const int fi = tid + it * 256;
                const int r = fi >> 4, c4 = (fi & 15) << 2;
                *(float4*)&KVs[r][c4] = *(const float4*)&src[r * HD_ + c4];
            }
        }
        __syncthreads();

        // scores: s[i][c] = Q[qg2*4+i] . K[jt+16c]
        float s[4][4] = {};
        #pragma unroll 4
        for (int d = 0; d < HD_; d += 4) {
            float4 qv[4], kv[4];
            #pragma unroll
            for (int i = 0; i < 4; ++i) qv[i] = *(const float4*)&Qs[qg2 * 4 + i][d];
            #pragma unroll
            for (int c = 0; c < 4; ++c) kv[c] = *(const float4*)&KVs[jt + 16 * c][d];
            #pragma unroll
            for (int i = 0; i < 4; ++i)
                #pragma unroll
                for (int c = 0; c < 4; ++c)
                    s[i][c] += qv[i].x * kv[c].x + qv[i].y * kv[c].y +
                               qv[i].z * kv[c].z + qv[i].w * kv[c].w;
        }

        // scale + causal mask + online softmax update
        const bool diag = (kb == qb);
        #pragma unroll
        for (int i = 0; i < 4; ++i) {
            const int qoff = qg2 * 4 + i;
            #pragma unroll
            for (int c = 0; c < 4; ++c) {
                const int joff = jt + 16 * c;
                s[i][c] = (diag && joff > qoff) ? -INFINITY : s[i][c] * SCALE;
            }
            float mx = fmaxf(fmaxf(s[i][0], s[i][1]), fmaxf(s[i][2], s[i][3]));
            mx = fmaxf(mx, __shfl_xor(mx, 1));
            mx = fmaxf(mx, __shfl_xor(mx, 2));
            mx = fmaxf(mx, __shfl_xor(mx, 4));
            mx = fmaxf(mx, __shfl_xor(mx, 8));
            const float mnew = fmaxf(m[i], mx);
            const float alpha = __expf(m[i] - mnew);
            float rs = 0.f;
            #pragma unroll
            for (int c = 0; c < 4; ++c) {
                const float p = __expf(s[i][c] - mnew);
                s[i][c] = p;
                rs += p;
            }
            rs += __shfl_xor(rs, 1);
            rs += __shfl_xor(rs, 2);
            rs += __shfl_xor(rs, 4);
            rs += __shfl_xor(rs, 8);
            l[i] = l[i] * alpha + rs;
            m[i] = mnew;
            O[i][0] *= alpha; O[i][1] *= alpha; O[i][2] *= alpha; O[i][3] *= alpha;
            // stash P
            #pragma unroll
            for (int c = 0; c < 4; ++c) Ps[qoff][jt + 16 * c] = s[i][c];
        }
        __syncthreads();   // K reads done + Ps visible

        {   // load V tile into the same buffer
            const float* src = vbase + (size_t)kb * 64 * HD_;
            #pragma unroll
            for (int it = 0; it < 4; ++it) {
                const int fi = tid + it * 256;
                const int r = fi >> 4, c4 = (fi & 15) << 2;
                *(float4*)&KVs[r][c4] = *(const float4*)&src[r * HD_ + c4];
            }
        }
        __syncthreads();

        // O[i][*] += P[q][j] * V[j][jt*4 + *]
        for (int j0 = 0; j0 < 64; j0 += 4) {
            float4 p4[4];
            #pragma unroll
            for (int i = 0; i < 4; ++i) p4[i] = *(const float4*)&Ps[qg2 * 4 + i][j0];
            #pragma unroll
            for (int jj = 0; jj < 4; ++jj) {
                const float4 vv = *(const float4*)&KVs[j0 + jj][jt << 2];
                #pragma unroll
                for (int i = 0; i < 4; ++i) {
                    const float pv = (jj == 0) ? p4[i].x : (jj == 1) ? p4[i].y
                                   : (jj == 2) ? p4[i].z : p4[i].w;
                    O[i][0] += pv * vv.x; O[i][1] += pv * vv.y;
                    O[i][2] += pv * vv.z; O[i][3] += pv * vv.w;
                }
            }
        }
    }

    // normalize + write ctx as [B, N, D_OUT] (heads re-interleaved)
    const int b = bh >> 4;
    const int h = bh & 15;
    #pragma unroll
    for (int i = 0; i < 4; ++i) {
        const float inv = 1.f / l[i];
        const int rq = qb * 64 + qg2 * 4 + i;
        float* dst = &ctx[((size_t)(b * N_ + rq)) * DOUT + h * HD_ + (jt << 2)];
        *(float4*)dst = make_float4(O[i][0] * inv, O[i][1] * inv,
                                    O[i][2] * inv, O[i][3] * inv);
    }
}

// ---------------------------------------------------------------------------
// Kernel 3: output projection.  out = ctx @ Wo + bo.  grid = (64, 16)
// ---------------------------------------------------------------------------
__global__ __launch_bounds__(256) void out_gemm(
    const float* __restrict__ ctx, const float* __restrict__ Wo,
    const float* __restrict__ bo, float* __restrict__ out)
{
    __shared__ float As[64][17];
    __shared__ float Bs[16][64];

    const int tid = threadIdx.x;
    const int tx = tid & 15, ty = tid >> 4;
    const int tileM = blockIdx.x * 64;
    const int tileN = blockIdx.y * 64;

    float acc[4][4] = {};

    const int la_r = tid >> 2;
    const int la_k = (tid & 3) << 2;
    const int lb_k = tid >> 4;
    const int lb_c = (tid & 15) << 2;

    for (int k0 = 0; k0 < DOUT; k0 += 16) {
        float4 a4 = *(const float4*)&ctx[(size_t)(tileM + la_r) * DOUT + k0 + la_k];
        As[la_r][la_k + 0] = a4.x; As[la_r][la_k + 1] = a4.y;
        As[la_r][la_k + 2] = a4.z; As[la_r][la_k + 3] = a4.w;
        *(float4*)&Bs[lb_k][lb_c] =
            *(const float4*)&Wo[(size_t)(k0 + lb_k) * DOUT + tileN + lb_c];
        __syncthreads();
        #pragma unroll
        for (int kk = 0; kk < 16; ++kk) {
            const float a0 = As[ty * 4 + 0][kk];
            const float a1 = As[ty * 4 + 1][kk];
            const float a2 = As[ty * 4 + 2][kk];
            const float a3 = As[ty * 4 + 3][kk];
            const float4 b4 = *(const float4*)&Bs[kk][tx << 2];
            acc[0][0] += a0 * b4.x; acc[0][1] += a0 * b4.y;
            acc[0][2] += a0 * b4.z; acc[0][3] += a0 * b4.w;
            acc[1][0] += a1 * b4.x; acc[1][1] += a1 * b4.y;
            acc[1][2] += a1 * b4.z; acc[1][3] += a1 * b4.w;
            acc[2][0] += a2 * b4.x; acc[2][1] += a2 * b4.y;
            acc[2][2] += a2 * b4.z; acc[2][3] += a2 * b4.w;
            acc[3][0] += a3 * b4.x; acc[3][1] += a3 * b4.y;
            acc[3][2] += a3 * b4.z; acc[3][3] += a3 * b4.w;
        }
        __syncthreads();
    }

    const int c0 = tileN + (tx << 2);
    const float4 bv = *(const float4*)&bo[c0];
    #pragma unroll
    for (int i = 0; i < 4; ++i) {
        const int r = tileM + ty * 4 + i;
        *(float4*)&out[(size_t)r * DOUT + c0] =
            make_float4(acc[i][0] + bv.x, acc[i][1] + bv.y,
                        acc[i][2] + bv.z, acc[i][3] + bv.w);
    }
}

// ---------------------------------------------------------------------------
extern "C" void kernel_launch(void* const* d_in, const int* in_sizes, int n_in,
                              void* d_out, int out_size, void* d_ws, size_t ws_size,
                              hipStream_t stream)
{
    const float* x  = (const float*)d_in[0];
    const float* Wq = (const float*)d_in[1];
    const float* Wk = (const float*)d_in[2];
    const float* Wv = (const float*)d_in[3];
    const float* Wo = (const float*)d_in[4];
    const float* bo = (const float*)d_in[5];
    float* out = (float*)d_out;

    const size_t per = (size_t)B_ * H_ * N_ * HD_;   // 4,194,304 floats
    float* qbuf = (float*)d_ws;
    float* kbuf = qbuf + per;
    float* vbuf = kbuf + per;
    float* ctx  = vbuf + per;

    qkv_gemm<<<dim3(M_ / 64, 3 * DOUT / 64), 256, 0, stream>>>(
        x, Wq, Wk, Wv, qbuf, kbuf, vbuf);
    attn_fwd<<<dim3(N_ / 64, B_ * H_), 256, 0, stream>>>(qbuf, kbuf, vbuf, ctx);
    out_gemm<<<dim3(M_ / 64, DOUT / 64), 256, 0, stream>>>(ctx, Wo, bo, out);
}

// Round 2
// 205.215 us; speedup vs baseline: 5.1073x; 5.1073x over previous
//
#include <hip/hip_runtime.h>
#include <math.h>
#include <stdint.h>

#define B_ 2
#define N_ 2048
#define D_ 1024
#define H_ 16
#define HD_ 64
#define M_ (B_ * N_)   // 4096

typedef __bf16 bf16x8 __attribute__((ext_vector_type(8)));
typedef float f32x4 __attribute__((ext_vector_type(4)));

__device__ __forceinline__ ushort f2bf(float f) {
    uint32_t u = __builtin_bit_cast(uint32_t, f);
    u += 0x7fff + ((u >> 16) & 1);          // RNE
    return (ushort)(u >> 16);
}

// ---------------------------------------------------------------------------
// Convert x (fp32) -> bf16, same layout [M][D]
// ---------------------------------------------------------------------------
__global__ __launch_bounds__(256) void cvt_x(const float* __restrict__ x,
                                             ushort* __restrict__ xb) {
    int i = blockIdx.x * 256 + threadIdx.x;          // one float4 each
    float4 v = ((const float4*)x)[i];
    ushort4 o;
    o.x = f2bf(v.x); o.y = f2bf(v.y); o.z = f2bf(v.z); o.w = f2bf(v.w);
    ((ushort4*)xb)[i] = o;
}

// ---------------------------------------------------------------------------
// Convert + transpose weights: W[k][n] fp32 -> Wt[n][k] bf16.
// 32x32 tiles, grid (32, 32, 4); z selects Wq/Wk/Wv/Wo.
// ---------------------------------------------------------------------------
__global__ __launch_bounds__(256) void cvt_w(const float* __restrict__ W0,
                                             const float* __restrict__ W1,
                                             const float* __restrict__ W2,
                                             const float* __restrict__ W3,
                                             ushort* __restrict__ Wt) {
    __shared__ float T[32][33];
    const float* W = (blockIdx.z == 0) ? W0 : (blockIdx.z == 1) ? W1
                   : (blockIdx.z == 2) ? W2 : W3;
    ushort* out = Wt + (size_t)blockIdx.z * D_ * D_;
    const int t = threadIdx.x;
    const int k0 = blockIdx.x * 32, n0 = blockIdx.y * 32;
    {
        int kl = t >> 3, nl = (t & 7) * 4;
        float4 v = *(const float4*)&W[(size_t)(k0 + kl) * D_ + n0 + nl];
        T[kl][nl] = v.x; T[kl][nl + 1] = v.y; T[kl][nl + 2] = v.z; T[kl][nl + 3] = v.w;
    }
    __syncthreads();
    {
        int nl = t >> 3, k4 = (t & 7) * 4;
        ushort4 o;
        o.x = f2bf(T[k4 + 0][nl]); o.y = f2bf(T[k4 + 1][nl]);
        o.z = f2bf(T[k4 + 2][nl]); o.w = f2bf(T[k4 + 3][nl]);
        *(ushort4*)&out[(size_t)(n0 + nl) * D_ + k0 + k4] = o;
    }
}

// ---------------------------------------------------------------------------
// Shared MFMA GEMM mainloop: C128x128 += A[M][K] * Bt[n][k]^T.
// 256 threads = 4 waves (2x2 of 64x64). BK=32, LDS rows padded to 40 ushort.
// ---------------------------------------------------------------------------
#define BK 32
#define PAD 40

__device__ __forceinline__ void gemm_tile(const ushort* __restrict__ A,
                                          const ushort* __restrict__ Bt,
                                          int K, int tileM, int tileN,
                                          ushort* As, ushort* Bs,
                                          f32x4 acc[4][4]) {
    const int t = threadIdx.x;
    const int l = t & 63;
    const int w = t >> 6;
    const int wr = w >> 1, wc = w & 1;
    const int li = l & 15, lg = l >> 4;

    for (int k0 = 0; k0 < K; k0 += BK) {
        __syncthreads();
        #pragma unroll
        for (int it = 0; it < 2; ++it) {
            int ci = t + 256 * it;
            int r = ci >> 2, c = (ci & 3) * 8;
            *(uint4*)&As[r * PAD + c] = *(const uint4*)&A[(size_t)(tileM + r) * K + k0 + c];
            *(uint4*)&Bs[r * PAD + c] = *(const uint4*)&Bt[(size_t)(tileN + r) * K + k0 + c];
        }
        __syncthreads();
        bf16x8 a[4], b[4];
        #pragma unroll
        for (int m = 0; m < 4; ++m)
            a[m] = *(const bf16x8*)&As[(wr * 64 + m * 16 + li) * PAD + lg * 8];
        #pragma unroll
        for (int n = 0; n < 4; ++n)
            b[n] = *(const bf16x8*)&Bs[(wc * 64 + n * 16 + li) * PAD + lg * 8];
        #pragma unroll
        for (int m = 0; m < 4; ++m)
            #pragma unroll
            for (int n = 0; n < 4; ++n)
                acc[m][n] = __builtin_amdgcn_mfma_f32_16x16x32_bf16(a[m], b[n], acc[m][n], 0, 0, 0);
    }
}

// ---------------------------------------------------------------------------
// QKV projection: xb[M][D] * Wt{q,k,v} -> q/k/v bf16 in [B,H,N,HD].
// Q pre-scaled by 1/sqrt(HD) = 0.125 (exact in bf16).
// grid (32, 24): y -> {w 0..2} x {8 n-tiles}
// ---------------------------------------------------------------------------
__global__ __launch_bounds__(256) void qkv_gemm(const ushort* __restrict__ xb,
                                                const ushort* __restrict__ Wt,
                                                ushort* __restrict__ q,
                                                ushort* __restrict__ k,
                                                ushort* __restrict__ v) {
    __shared__ ushort As[128 * PAD];
    __shared__ ushort Bs[128 * PAD];
    f32x4 acc[4][4];
    #pragma unroll
    for (int m = 0; m < 4; ++m)
        #pragma unroll
        for (int n = 0; n < 4; ++n)
            acc[m][n] = (f32x4){0.f, 0.f, 0.f, 0.f};

    const int tileM = blockIdx.x * 128;
    const int wsel = blockIdx.y >> 3;
    const int tileN = (blockIdx.y & 7) * 128;
    const ushort* Bmat = Wt + (size_t)wsel * D_ * D_;

    gemm_tile(xb, Bmat, D_, tileM, tileN, As, Bs, acc);

    ushort* out = (wsel == 0) ? q : (wsel == 1) ? k : v;
    const float scale = (wsel == 0) ? 0.125f : 1.0f;
    const int l = threadIdx.x & 63, w = threadIdx.x >> 6;
    const int wr = w >> 1, wc = w & 1;
    const int li = l & 15, lg = l >> 4;
    #pragma unroll
    for (int m = 0; m < 4; ++m)
        #pragma unroll
        for (int n = 0; n < 4; ++n)
            #pragma unroll
            for (int r = 0; r < 4; ++r) {
                int grow = tileM + wr * 64 + m * 16 + lg * 4 + r;
                int gcol = tileN + wc * 64 + n * 16 + li;
                int b = grow >> 11, nn = grow & (N_ - 1);
                int h = gcol >> 6, hd = gcol & 63;
                out[((size_t)(b * H_ + h) * N_ + nn) * HD_ + hd] = f2bf(acc[m][n][r] * scale);
            }
}

// ---------------------------------------------------------------------------
// Output projection: ctx[M][D] * Wot -> out fp32 [M][D] + bias. grid (32, 8)
// ---------------------------------------------------------------------------
__global__ __launch_bounds__(256) void out_gemm(const ushort* __restrict__ ctx,
                                                const ushort* __restrict__ Wt,
                                                const float* __restrict__ bo,
                                                float* __restrict__ outp) {
    __shared__ ushort As[128 * PAD];
    __shared__ ushort Bs[128 * PAD];
    f32x4 acc[4][4];
    #pragma unroll
    for (int m = 0; m < 4; ++m)
        #pragma unroll
        for (int n = 0; n < 4; ++n)
            acc[m][n] = (f32x4){0.f, 0.f, 0.f, 0.f};

    const int tileM = blockIdx.x * 128;
    const int tileN = blockIdx.y * 128;
    const ushort* Bmat = Wt + (size_t)3 * D_ * D_;   // Wo^T

    gemm_tile(ctx, Bmat, D_, tileM, tileN, As, Bs, acc);

    const int l = threadIdx.x & 63, w = threadIdx.x >> 6;
    const int wr = w >> 1, wc = w & 1;
    const int li = l & 15, lg = l >> 4;
    #pragma unroll
    for (int n = 0; n < 4; ++n) {
        float bias = bo[tileN + wc * 64 + n * 16 + li];
        #pragma unroll
        for (int m = 0; m < 4; ++m)
            #pragma unroll
            for (int r = 0; r < 4; ++r) {
                int grow = tileM + wr * 64 + m * 16 + lg * 4 + r;
                int gcol = tileN + wc * 64 + n * 16 + li;
                outp[(size_t)grow * D_ + gcol] = acc[m][n][r] + bias;
            }
    }
}

// ---------------------------------------------------------------------------
// MFMA causal flash attention. Q pre-scaled. bf16 in, bf16 ctx out.
// Block = (bh, 64 q-rows), 4 waves, wave = 16 q-rows.
// S-frag/O-frag D-layout: row=(l>>4)*4+reg, col=l&15  [m89 verified]
// A/B-frags: 8 contiguous bf16 per lane at [row=l&15][k=(l>>4)*8].
// grid (32, 32); qb reversed so heavy blocks launch first.
// ---------------------------------------------------------------------------
__global__ __launch_bounds__(256) void attn_fwd(const ushort* __restrict__ q,
                                                const ushort* __restrict__ k,
                                                const ushort* __restrict__ v,
                                                ushort* __restrict__ ctx) {
    __shared__ ushort Ks[64][72];       // K tile, row-major [j][d]
    __shared__ ushort Vt[64][72];       // V tile transposed [d][j]
    __shared__ ushort Ps[4][16][72];    // per-wave P [qrow][j]

    const int t = threadIdx.x;
    const int l = t & 63;
    const int w = t >> 6;
    const int li = l & 15, lg = l >> 4;
    const int qb = gridDim.x - 1 - blockIdx.x;
    const int bh = blockIdx.y;

    const ushort* Qg = q + (size_t)bh * N_ * HD_;
    const ushort* Kg = k + (size_t)bh * N_ * HD_;
    const ushort* Vg = v + (size_t)bh * N_ * HD_;

    // Q fragments for this wave's 16 rows (k-halves 0..31, 32..63)
    bf16x8 aq[2];
    #pragma unroll
    for (int tk = 0; tk < 2; ++tk)
        aq[tk] = *(const bf16x8*)&Qg[(size_t)(qb * 64 + w * 16 + li) * HD_ + tk * 32 + lg * 8];

    f32x4 od[4];
    #pragma unroll
    for (int db = 0; db < 4; ++db) od[db] = (f32x4){0.f, 0.f, 0.f, 0.f};
    float mrow[4], lrow[4];
    #pragma unroll
    for (int r = 0; r < 4; ++r) { mrow[r] = -INFINITY; lrow[r] = 0.f; }

    for (int kb = 0; kb <= qb; ++kb) {
        __syncthreads();                 // prior tile's LDS reads done
        // stage K tile (coalesced 16B)
        #pragma unroll
        for (int it = 0; it < 2; ++it) {
            int ci = t + 256 * it;
            int r = ci >> 3, c = (ci & 7) * 8;
            *(uint4*)&Ks[r][c] = *(const uint4*)&Kg[(size_t)(kb * 64 + r) * HD_ + c];
        }
        // stage V transposed: wave w fills columns j in [16w, 16w+16)
        {
            uint32_t p0, p1, p2, p3, p4, p5, p6, p7;
            const ushort* vb = Vg + (size_t)(kb * 64 + w * 16) * HD_ + l;
            #define LDP(J) ((uint32_t)vb[(2*(J)) * HD_] | ((uint32_t)vb[(2*(J)+1) * HD_] << 16))
            p0 = LDP(0); p1 = LDP(1); p2 = LDP(2); p3 = LDP(3);
            p4 = LDP(4); p5 = LDP(5); p6 = LDP(6); p7 = LDP(7);
            #undef LDP
            uint4 w0; w0.x = p0; w0.y = p1; w0.z = p2; w0.w = p3;
            uint4 w1; w1.x = p4; w1.y = p5; w1.z = p6; w1.w = p7;
            *(uint4*)&Vt[l][w * 16 + 0] = w0;
            *(uint4*)&Vt[l][w * 16 + 8] = w1;
        }
        __syncthreads();

        // S = Q*K^T (four 16-col blocks, K=64 via two mfma)
        f32x4 s[4];
        #pragma unroll
        for (int c = 0; c < 4; ++c) {
            s[c] = (f32x4){0.f, 0.f, 0.f, 0.f};
            #pragma unroll
            for (int tk = 0; tk < 2; ++tk) {
                bf16x8 bk = *(const bf16x8*)&Ks[c * 16 + li][tk * 32 + lg * 8];
                s[c] = __builtin_amdgcn_mfma_f32_16x16x32_bf16(aq[tk], bk, s[c], 0, 0, 0);
            }
        }

        // online softmax (rows live on lanes sharing lg; reduce over li)
        const bool diag = (kb == qb);
        #pragma unroll
        for (int r = 0; r < 4; ++r) {
            const int qloc = w * 16 + lg * 4 + r;
            float sv[4];
            #pragma unroll
            for (int c = 0; c < 4; ++c) {
                int jloc = c * 16 + li;
                sv[c] = (diag && jloc > qloc) ? -INFINITY : s[c][r];
            }
            float mx = fmaxf(fmaxf(sv[0], sv[1]), fmaxf(sv[2], sv[3]));
            mx = fmaxf(mx, __shfl_xor(mx, 1));
            mx = fmaxf(mx, __shfl_xor(mx, 2));
            mx = fmaxf(mx, __shfl_xor(mx, 4));
            mx = fmaxf(mx, __shfl_xor(mx, 8));
            const float mnew = fmaxf(mrow[r], mx);
            const float alpha = __expf(mrow[r] - mnew);
            float rs = 0.f;
            #pragma unroll
            for (int c = 0; c < 4; ++c) {
                float p = __expf(sv[c] - mnew);
                rs += p;
                Ps[w][lg * 4 + r][c * 16 + li] = f2bf(p);
            }
            rs += __shfl_xor(rs, 1);
            rs += __shfl_xor(rs, 2);
            rs += __shfl_xor(rs, 4);
            rs += __shfl_xor(rs, 8);
            lrow[r] = lrow[r] * alpha + rs;
            mrow[r] = mnew;
            #pragma unroll
            for (int db = 0; db < 4; ++db) od[db][r] *= alpha;
        }
        // (same-wave LDS write->read; compiler orders via lgkmcnt)

        // O += P*V  (A = P rows from Ps, B = V^T rows from Vt)
        #pragma unroll
        for (int tj = 0; tj < 2; ++tj) {
            bf16x8 pa = *(const bf16x8*)&Ps[w][li][tj * 32 + lg * 8];
            #pragma unroll
            for (int db = 0; db < 4; ++db) {
                bf16x8 bv = *(const bf16x8*)&Vt[db * 16 + li][tj * 32 + lg * 8];
                od[db] = __builtin_amdgcn_mfma_f32_16x16x32_bf16(pa, bv, od[db], 0, 0, 0);
            }
        }
    }

    // epilogue: normalize, write ctx bf16 [B*N][D] with heads interleaved
    const int b = bh >> 4, h = bh & 15;
    #pragma unroll
    for (int r = 0; r < 4; ++r) {
        const float inv = 1.f / lrow[r];
        const int grow = qb * 64 + w * 16 + lg * 4 + r;
        #pragma unroll
        for (int db = 0; db < 4; ++db)
            ctx[((size_t)(b * N_ + grow)) * D_ + h * 64 + db * 16 + li] = f2bf(od[db][r] * inv);
    }
}

// ---------------------------------------------------------------------------
extern "C" void kernel_launch(void* const* d_in, const int* in_sizes, int n_in,
                              void* d_out, int out_size, void* d_ws, size_t ws_size,
                              hipStream_t stream) {
    (void)in_sizes; (void)n_in; (void)out_size; (void)ws_size;
    const float* x  = (const float*)d_in[0];
    const float* Wq = (const float*)d_in[1];
    const float* Wk = (const float*)d_in[2];
    const float* Wv = (const float*)d_in[3];
    const float* Wo = (const float*)d_in[4];
    const float* bo = (const float*)d_in[5];
    float* outp = (float*)d_out;

    // workspace layout (bf16 = ushort)
    ushort* xb  = (ushort*)d_ws;                       //  8 MB: [4096][1024]
    ushort* Wt  = xb + (size_t)M_ * D_;                //  8 MB: 4x [1024][1024] (n-major)
    ushort* qb  = Wt + (size_t)4 * D_ * D_;            //  8 MB: [B,H,N,HD]
    ushort* kb  = qb + (size_t)B_ * H_ * N_ * HD_;     //  8 MB
    ushort* vb  = kb + (size_t)B_ * H_ * N_ * HD_;     //  8 MB
    ushort* ctx = vb + (size_t)B_ * H_ * N_ * HD_;     //  8 MB: [4096][1024]

    cvt_x<<<dim3((M_ * D_ / 4) / 256), 256, 0, stream>>>(x, xb);
    cvt_w<<<dim3(32, 32, 4), 256, 0, stream>>>(Wq, Wk, Wv, Wo, Wt);
    qkv_gemm<<<dim3(32, 24), 256, 0, stream>>>(xb, Wt, qb, kb, vb);
    attn_fwd<<<dim3(32, 32), 256, 0, stream>>>(qb, kb, vb, ctx);
    out_gemm<<<dim3(32, 8), 256, 0, stream>>>(ctx, Wt, bo, outp);
}

// Round 3
// 204.960 us; speedup vs baseline: 5.1136x; 1.0012x over previous
//
#include <hip/hip_runtime.h>
#include <math.h>
#include <stdint.h>

#define B_ 2
#define N_ 2048
#define D_ 1024
#define H_ 16
#define HD_ 64
#define M_ (B_ * N_)   // 4096

typedef __bf16 bf16x8 __attribute__((ext_vector_type(8)));
typedef float f32x4 __attribute__((ext_vector_type(4)));

__device__ __forceinline__ ushort f2bf(float f) {
    uint32_t u = __builtin_bit_cast(uint32_t, f);
    u += 0x7fff + ((u >> 16) & 1);          // RNE
    return (ushort)(u >> 16);
}

// async global->LDS, 16B per lane; LDS dest = wave-uniform base + lane*16
__device__ __forceinline__ void glds16(const ushort* g, ushort* l) {
    __builtin_amdgcn_global_load_lds(
        (const __attribute__((address_space(1))) uint32_t*)g,
        (__attribute__((address_space(3))) uint32_t*)l, 16, 0, 0);
}

// ---------------------------------------------------------------------------
// Convert x (fp32) -> bf16, same layout [M][D]
// ---------------------------------------------------------------------------
__global__ __launch_bounds__(256) void cvt_x(const float* __restrict__ x,
                                             ushort* __restrict__ xb) {
    int i = blockIdx.x * 256 + threadIdx.x;
    float4 v = ((const float4*)x)[i];
    ushort4 o;
    o.x = f2bf(v.x); o.y = f2bf(v.y); o.z = f2bf(v.z); o.w = f2bf(v.w);
    ((ushort4*)xb)[i] = o;
}

// ---------------------------------------------------------------------------
// Convert + transpose weights: W[k][n] fp32 -> Wt[n][k] bf16. grid (32,32,4)
// ---------------------------------------------------------------------------
__global__ __launch_bounds__(256) void cvt_w(const float* __restrict__ W0,
                                             const float* __restrict__ W1,
                                             const float* __restrict__ W2,
                                             const float* __restrict__ W3,
                                             ushort* __restrict__ Wt) {
    __shared__ float T[32][33];
    const float* W = (blockIdx.z == 0) ? W0 : (blockIdx.z == 1) ? W1
                   : (blockIdx.z == 2) ? W2 : W3;
    ushort* out = Wt + (size_t)blockIdx.z * D_ * D_;
    const int t = threadIdx.x;
    const int k0 = blockIdx.x * 32, n0 = blockIdx.y * 32;
    {
        int kl = t >> 3, nl = (t & 7) * 4;
        float4 v = *(const float4*)&W[(size_t)(k0 + kl) * D_ + n0 + nl];
        T[kl][nl] = v.x; T[kl][nl + 1] = v.y; T[kl][nl + 2] = v.z; T[kl][nl + 3] = v.w;
    }
    __syncthreads();
    {
        int nl = t >> 3, k4 = (t & 7) * 4;
        ushort4 o;
        o.x = f2bf(T[k4 + 0][nl]); o.y = f2bf(T[k4 + 1][nl]);
        o.z = f2bf(T[k4 + 2][nl]); o.w = f2bf(T[k4 + 3][nl]);
        *(ushort4*)&out[(size_t)(n0 + nl) * D_ + k0 + k4] = o;
    }
}

// ---------------------------------------------------------------------------
// Transpose V: [B,H,N,HD] -> [B,H,HD,N]. 64x64 tiles. grid (32, 32)
// ---------------------------------------------------------------------------
__global__ __launch_bounds__(256) void transp_v(const ushort* __restrict__ vb,
                                                ushort* __restrict__ vt) {
    __shared__ ushort T[64][72];
    const int t = threadIdx.x;
    const int nt = blockIdx.x, bh = blockIdx.y;
    const ushort* src = vb + ((size_t)bh * N_ + nt * 64) * HD_;
    #pragma unroll
    for (int it = 0; it < 2; ++it) {
        int fi = it * 256 + t;
        int r = fi >> 3, c = (fi & 7) * 8;
        *(uint4*)&T[r][c] = *(const uint4*)&src[(size_t)r * HD_ + c];
    }
    __syncthreads();
    ushort* dst = vt + (size_t)bh * HD_ * N_ + nt * 64;
    #pragma unroll
    for (int it = 0; it < 2; ++it) {
        int fi = it * 256 + t;
        int hd = fi >> 3, n0 = (fi & 7) * 8;
        uint4 o;
        o.x = (uint32_t)T[n0 + 0][hd] | ((uint32_t)T[n0 + 1][hd] << 16);
        o.y = (uint32_t)T[n0 + 2][hd] | ((uint32_t)T[n0 + 3][hd] << 16);
        o.z = (uint32_t)T[n0 + 4][hd] | ((uint32_t)T[n0 + 5][hd] << 16);
        o.w = (uint32_t)T[n0 + 6][hd] | ((uint32_t)T[n0 + 7][hd] << 16);
        *(uint4*)&dst[(size_t)hd * N_ + n0] = o;
    }
}

// ---------------------------------------------------------------------------
// MFMA GEMM mainloop (m97 structure): 128x128 tile, BK=32, linear LDS
// [128][32] bf16 staged via global_load_lds w=16, both-sides XOR swizzle
// (16B slot ^ (row&3)).  256 threads = 4 waves (2x2 of 64x64).
// ---------------------------------------------------------------------------
#define BK 32

__device__ __forceinline__ void gemm_tile(const ushort* __restrict__ A,
                                          const ushort* __restrict__ Bt,
                                          int K, int tileM, int tileN,
                                          ushort* As, ushort* Bs,
                                          f32x4 acc[4][4]) {
    const int t = threadIdx.x;
    const int l = t & 63;
    const int w = __builtin_amdgcn_readfirstlane(t >> 6);
    const int wr = w >> 1, wc = w & 1;
    const int li = l & 15, lg = l >> 4;
    const int lr = l >> 2;                    // row-within-chunk 0..15
    const int colu = (((l & 3) ^ (lr & 3)) << 3);   // inverse-swizzled src col
    const int swz = (li & 3) << 3;            // read-side xor (ushort units)

    for (int k0 = 0; k0 < K; k0 += BK) {
        __syncthreads();
        #pragma unroll
        for (int it = 0; it < 2; ++it) {
            const int c2 = it * 4 + w;
            const int row = c2 * 16 + lr;
            glds16(&A[(size_t)(tileM + row) * K + k0 + colu], &As[c2 * 512]);
            glds16(&Bt[(size_t)(tileN + row) * K + k0 + colu], &Bs[c2 * 512]);
        }
        __syncthreads();                      // compiler drains vmcnt here
        bf16x8 a[4], b[4];
        #pragma unroll
        for (int m = 0; m < 4; ++m)
            a[m] = *(const bf16x8*)&As[(wr * 64 + m * 16 + li) * 32 + ((lg << 3) ^ swz)];
        #pragma unroll
        for (int n = 0; n < 4; ++n)
            b[n] = *(const bf16x8*)&Bs[(wc * 64 + n * 16 + li) * 32 + ((lg << 3) ^ swz)];
        #pragma unroll
        for (int m = 0; m < 4; ++m)
            #pragma unroll
            for (int n = 0; n < 4; ++n)
                acc[m][n] = __builtin_amdgcn_mfma_f32_16x16x32_bf16(a[m], b[n], acc[m][n], 0, 0, 0);
    }
}

// ---------------------------------------------------------------------------
// QKV projection -> q/k/v bf16 in [B,H,N,HD]; Q pre-scaled by
// 0.125*log2(e) (exp2-domain softmax). grid (32, 24)
// ---------------------------------------------------------------------------
#define QSCALE 0.180336880f   // 1/sqrt(64) * log2(e)

__global__ __launch_bounds__(256) void qkv_gemm(const ushort* __restrict__ xb,
                                                const ushort* __restrict__ Wt,
                                                ushort* __restrict__ q,
                                                ushort* __restrict__ k,
                                                ushort* __restrict__ v) {
    __shared__ ushort As[128 * 32];
    __shared__ ushort Bs[128 * 32];
    f32x4 acc[4][4];
    #pragma unroll
    for (int m = 0; m < 4; ++m)
        #pragma unroll
        for (int n = 0; n < 4; ++n)
            acc[m][n] = (f32x4){0.f, 0.f, 0.f, 0.f};

    const int tileM = blockIdx.x * 128;
    const int wsel = blockIdx.y >> 3;
    const int tileN = (blockIdx.y & 7) * 128;
    const ushort* Bmat = Wt + (size_t)wsel * D_ * D_;

    gemm_tile(xb, Bmat, D_, tileM, tileN, As, Bs, acc);

    ushort* out = (wsel == 0) ? q : (wsel == 1) ? k : v;
    const float scale = (wsel == 0) ? QSCALE : 1.0f;
    const int l = threadIdx.x & 63, w = threadIdx.x >> 6;
    const int wr = w >> 1, wc = w & 1;
    const int li = l & 15, lg = l >> 4;
    #pragma unroll
    for (int m = 0; m < 4; ++m)
        #pragma unroll
        for (int n = 0; n < 4; ++n)
            #pragma unroll
            for (int r = 0; r < 4; ++r) {
                int grow = tileM + wr * 64 + m * 16 + lg * 4 + r;
                int gcol = tileN + wc * 64 + n * 16 + li;
                int b = grow >> 11, nn = grow & (N_ - 1);
                int h = gcol >> 6, hd = gcol & 63;
                out[((size_t)(b * H_ + h) * N_ + nn) * HD_ + hd] = f2bf(acc[m][n][r] * scale);
            }
}

// ---------------------------------------------------------------------------
// Output projection: ctx[M][D] * Wo^T + bo -> fp32 out. grid (32, 8)
// ---------------------------------------------------------------------------
__global__ __launch_bounds__(256) void out_gemm(const ushort* __restrict__ ctx,
                                                const ushort* __restrict__ Wt,
                                                const float* __restrict__ bo,
                                                float* __restrict__ outp) {
    __shared__ ushort As[128 * 32];
    __shared__ ushort Bs[128 * 32];
    f32x4 acc[4][4];
    #pragma unroll
    for (int m = 0; m < 4; ++m)
        #pragma unroll
        for (int n = 0; n < 4; ++n)
            acc[m][n] = (f32x4){0.f, 0.f, 0.f, 0.f};

    const int tileM = blockIdx.x * 128;
    const int tileN = blockIdx.y * 128;
    const ushort* Bmat = Wt + (size_t)3 * D_ * D_;   // Wo^T

    gemm_tile(ctx, Bmat, D_, tileM, tileN, As, Bs, acc);

    const int l = threadIdx.x & 63, w = threadIdx.x >> 6;
    const int wr = w >> 1, wc = w & 1;
    const int li = l & 15, lg = l >> 4;
    #pragma unroll
    for (int n = 0; n < 4; ++n) {
        float bias = bo[tileN + wc * 64 + n * 16 + li];
        #pragma unroll
        for (int m = 0; m < 4; ++m)
            #pragma unroll
            for (int r = 0; r < 4; ++r) {
                int grow = tileM + wr * 64 + m * 16 + lg * 4 + r;
                int gcol = tileN + wc * 64 + n * 16 + li;
                outp[(size_t)grow * D_ + gcol] = acc[m][n][r] + bias;
            }
    }
}

// ---------------------------------------------------------------------------
// Barrier-free MFMA causal flash attention.
// K read direct from global [B,H,N,HD]; V^T direct from [B,H,HD,N] (both
// L1/L2-resident, 256KB/head each).  Only per-wave P goes through LDS.
// 4 waves x 16 q-rows = 64 rows/block.  Softmax in exp2 domain (Q carries
// log2e).  Grid: 1024 flat; swizzled so each XCD owns 4 heads; qb reversed
// so heavy blocks start first.
// ---------------------------------------------------------------------------
__global__ __launch_bounds__(256) void attn_fwd(const ushort* __restrict__ q,
                                                const ushort* __restrict__ k,
                                                const ushort* __restrict__ vt,
                                                ushort* __restrict__ ctx) {
    __shared__ ushort Ps[4][16][72];

    const int t = threadIdx.x;
    const int l = t & 63;
    const int w = t >> 6;
    const int li = l & 15, lg = l >> 4;
    const int f = blockIdx.x;                       // 0..1023
    const int bh = ((f & 7) << 2) | ((f >> 3) & 3); // XCD i owns heads 4i..4i+3
    const int qb = 31 - (f >> 5);                   // heavy tiles first

    const ushort* Qg = q + (size_t)bh * N_ * HD_;
    const ushort* Kg = k + (size_t)bh * N_ * HD_;
    const ushort* Vg = vt + (size_t)bh * HD_ * N_;

    bf16x8 aq[2];
    #pragma unroll
    for (int tk = 0; tk < 2; ++tk)
        aq[tk] = *(const bf16x8*)&Qg[(size_t)(qb * 64 + w * 16 + li) * HD_ + tk * 32 + lg * 8];

    f32x4 od[4];
    #pragma unroll
    for (int db = 0; db < 4; ++db) od[db] = (f32x4){0.f, 0.f, 0.f, 0.f};
    float mrow[4], lrow[4];
    #pragma unroll
    for (int r = 0; r < 4; ++r) { mrow[r] = -INFINITY; lrow[r] = 0.f; }

    for (int kb = 0; kb <= qb; ++kb) {
        const ushort* Kt = Kg + (size_t)kb * 64 * HD_;

        // S = Q*K^T, four 16-key column blocks, K-frags direct from global
        f32x4 s[4];
        #pragma unroll
        for (int c = 0; c < 4; ++c) {
            s[c] = (f32x4){0.f, 0.f, 0.f, 0.f};
            #pragma unroll
            for (int tk = 0; tk < 2; ++tk) {
                bf16x8 bk = *(const bf16x8*)&Kt[(size_t)(c * 16 + li) * HD_ + tk * 32 + lg * 8];
                s[c] = __builtin_amdgcn_mfma_f32_16x16x32_bf16(aq[tk], bk, s[c], 0, 0, 0);
            }
        }

        // online softmax (exp2 domain); rows on lanes sharing lg, reduce over li
        const bool diag = (kb == qb);
        #pragma unroll
        for (int r = 0; r < 4; ++r) {
            const int qloc = w * 16 + lg * 4 + r;
            float sv[4];
            #pragma unroll
            for (int c = 0; c < 4; ++c) {
                int jloc = c * 16 + li;
                sv[c] = (diag && jloc > qloc) ? -INFINITY : s[c][r];
            }
            float mx = fmaxf(fmaxf(sv[0], sv[1]), fmaxf(sv[2], sv[3]));
            mx = fmaxf(mx, __shfl_xor(mx, 1));
            mx = fmaxf(mx, __shfl_xor(mx, 2));
            mx = fmaxf(mx, __shfl_xor(mx, 4));
            mx = fmaxf(mx, __shfl_xor(mx, 8));
            const float mnew = fmaxf(mrow[r], mx);
            const float alpha = exp2f(mrow[r] - mnew);
            float rs = 0.f;
            #pragma unroll
            for (int c = 0; c < 4; ++c) {
                float p = exp2f(sv[c] - mnew);
                rs += p;
                Ps[w][lg * 4 + r][c * 16 + li] = f2bf(p);
            }
            rs += __shfl_xor(rs, 1);
            rs += __shfl_xor(rs, 2);
            rs += __shfl_xor(rs, 4);
            rs += __shfl_xor(rs, 8);
            lrow[r] = lrow[r] * alpha + rs;
            mrow[r] = mnew;
            #pragma unroll
            for (int db = 0; db < 4; ++db) od[db][r] *= alpha;
        }
        // same-wave LDS RAW -> ordered by lgkmcnt, no barrier needed

        // O += P * V   (A = P rows from LDS, B = V^T rows direct from global)
        #pragma unroll
        for (int tj = 0; tj < 2; ++tj) {
            bf16x8 pa = *(const bf16x8*)&Ps[w][li][tj * 32 + lg * 8];
            #pragma unroll
            for (int db = 0; db < 4; ++db) {
                bf16x8 bv = *(const bf16x8*)&Vg[(size_t)(db * 16 + li) * N_ + kb * 64 + tj * 32 + lg * 8];
                od[db] = __builtin_amdgcn_mfma_f32_16x16x32_bf16(pa, bv, od[db], 0, 0, 0);
            }
        }
    }

    // epilogue: normalize, write ctx bf16 [B*N][D] with heads interleaved
    const int b = bh >> 4, h = bh & 15;
    #pragma unroll
    for (int r = 0; r < 4; ++r) {
        const float inv = 1.f / lrow[r];
        const int grow = qb * 64 + w * 16 + lg * 4 + r;
        #pragma unroll
        for (int db = 0; db < 4; ++db)
            ctx[((size_t)(b * N_ + grow)) * D_ + h * 64 + db * 16 + li] = f2bf(od[db][r] * inv);
    }
}

// ---------------------------------------------------------------------------
extern "C" void kernel_launch(void* const* d_in, const int* in_sizes, int n_in,
                              void* d_out, int out_size, void* d_ws, size_t ws_size,
                              hipStream_t stream) {
    (void)in_sizes; (void)n_in; (void)out_size; (void)ws_size;
    const float* x  = (const float*)d_in[0];
    const float* Wq = (const float*)d_in[1];
    const float* Wk = (const float*)d_in[2];
    const float* Wv = (const float*)d_in[3];
    const float* Wo = (const float*)d_in[4];
    const float* bo = (const float*)d_in[5];
    float* outp = (float*)d_out;

    ushort* xb  = (ushort*)d_ws;                       //  8 MB
    ushort* Wt  = xb + (size_t)M_ * D_;                //  8 MB (4x 1024^2, n-major)
    ushort* qb  = Wt + (size_t)4 * D_ * D_;            //  8 MB [B,H,N,HD]
    ushort* kb  = qb + (size_t)B_ * H_ * N_ * HD_;     //  8 MB [B,H,N,HD]
    ushort* vb  = kb + (size_t)B_ * H_ * N_ * HD_;     //  8 MB [B,H,N,HD]
    ushort* vtb = vb + (size_t)B_ * H_ * N_ * HD_;     //  8 MB [B,H,HD,N]
    ushort* ctx = vtb + (size_t)B_ * H_ * N_ * HD_;    //  8 MB [M][D]

    cvt_x<<<dim3((M_ * D_ / 4) / 256), 256, 0, stream>>>(x, xb);
    cvt_w<<<dim3(32, 32, 4), 256, 0, stream>>>(Wq, Wk, Wv, Wo, Wt);
    qkv_gemm<<<dim3(32, 24), 256, 0, stream>>>(xb, Wt, qb, kb, vb);
    transp_v<<<dim3(32, 32), 256, 0, stream>>>(vb, vtb);
    attn_fwd<<<dim3(1024), 256, 0, stream>>>(qb, kb, vtb, ctx);
    out_gemm<<<dim3(32, 8), 256, 0, stream>>>(ctx, Wt, bo, outp);
}

// Round 4
// 191.431 us; speedup vs baseline: 5.4750x; 1.0707x over previous
//
#include <hip/hip_runtime.h>
#include <math.h>
#include <stdint.h>

#define B_ 2
#define N_ 2048
#define D_ 1024
#define H_ 16
#define HD_ 64
#define M_ (B_ * N_)   // 4096

typedef __bf16 bf16x8 __attribute__((ext_vector_type(8)));
typedef float f32x4 __attribute__((ext_vector_type(4)));

__device__ __forceinline__ ushort bfbits(float f) {
    __bf16 h = (__bf16)f;
    return __builtin_bit_cast(ushort, h);
}

// async global->LDS, 16B per lane; LDS dest = wave-uniform base + lane*16
__device__ __forceinline__ void glds16(const ushort* g, ushort* l) {
    __builtin_amdgcn_global_load_lds(
        (const __attribute__((address_space(1))) uint32_t*)g,
        (__attribute__((address_space(3))) uint32_t*)l, 16, 0, 0);
}

// ---------------------------------------------------------------------------
// Convert x (fp32) -> bf16, same layout [M][D]
// ---------------------------------------------------------------------------
__global__ __launch_bounds__(256) void cvt_x(const float* __restrict__ x,
                                             ushort* __restrict__ xb) {
    int i = blockIdx.x * 256 + threadIdx.x;
    float4 v = ((const float4*)x)[i];
    ushort4 o;
    o.x = bfbits(v.x); o.y = bfbits(v.y); o.z = bfbits(v.z); o.w = bfbits(v.w);
    ((ushort4*)xb)[i] = o;
}

// ---------------------------------------------------------------------------
// Convert + transpose weights: W[k][n] fp32 -> Wt[n][k] bf16. grid (32,32,4)
// ---------------------------------------------------------------------------
__global__ __launch_bounds__(256) void cvt_w(const float* __restrict__ W0,
                                             const float* __restrict__ W1,
                                             const float* __restrict__ W2,
                                             const float* __restrict__ W3,
                                             ushort* __restrict__ Wt) {
    __shared__ float T[32][33];
    const float* W = (blockIdx.z == 0) ? W0 : (blockIdx.z == 1) ? W1
                   : (blockIdx.z == 2) ? W2 : W3;
    ushort* out = Wt + (size_t)blockIdx.z * D_ * D_;
    const int t = threadIdx.x;
    const int k0 = blockIdx.x * 32, n0 = blockIdx.y * 32;
    {
        int kl = t >> 3, nl = (t & 7) * 4;
        float4 v = *(const float4*)&W[(size_t)(k0 + kl) * D_ + n0 + nl];
        T[kl][nl] = v.x; T[kl][nl + 1] = v.y; T[kl][nl + 2] = v.z; T[kl][nl + 3] = v.w;
    }
    __syncthreads();
    {
        int nl = t >> 3, k4 = (t & 7) * 4;
        ushort4 o;
        o.x = bfbits(T[k4 + 0][nl]); o.y = bfbits(T[k4 + 1][nl]);
        o.z = bfbits(T[k4 + 2][nl]); o.w = bfbits(T[k4 + 3][nl]);
        *(ushort4*)&out[(size_t)(n0 + nl) * D_ + k0 + k4] = o;
    }
}

// ---------------------------------------------------------------------------
// Transpose V: [B,H,N,HD] -> [B,H,HD,N]. 64x64 tiles. grid (32, 32)
// ---------------------------------------------------------------------------
__global__ __launch_bounds__(256) void transp_v(const ushort* __restrict__ vb,
                                                ushort* __restrict__ vt) {
    __shared__ ushort T[64][72];
    const int t = threadIdx.x;
    const int nt = blockIdx.x, bh = blockIdx.y;
    const ushort* src = vb + ((size_t)bh * N_ + nt * 64) * HD_;
    #pragma unroll
    for (int it = 0; it < 2; ++it) {
        int fi = it * 256 + t;
        int r = fi >> 3, c = (fi & 7) * 8;
        *(uint4*)&T[r][c] = *(const uint4*)&src[(size_t)r * HD_ + c];
    }
    __syncthreads();
    ushort* dst = vt + (size_t)bh * HD_ * N_ + nt * 64;
    #pragma unroll
    for (int it = 0; it < 2; ++it) {
        int fi = it * 256 + t;
        int hd = fi >> 3, n0 = (fi & 7) * 8;
        uint4 o;
        o.x = (uint32_t)T[n0 + 0][hd] | ((uint32_t)T[n0 + 1][hd] << 16);
        o.y = (uint32_t)T[n0 + 2][hd] | ((uint32_t)T[n0 + 3][hd] << 16);
        o.z = (uint32_t)T[n0 + 4][hd] | ((uint32_t)T[n0 + 5][hd] << 16);
        o.w = (uint32_t)T[n0 + 6][hd] | ((uint32_t)T[n0 + 7][hd] << 16);
        *(uint4*)&dst[(size_t)hd * N_ + n0] = o;
    }
}

// ---------------------------------------------------------------------------
// MFMA GEMM mainloop (m97 structure): 128x128 tile, BK=32, linear LDS
// [128][32] bf16 staged via global_load_lds w=16, both-sides XOR swizzle.
// ---------------------------------------------------------------------------
#define BK 32

__device__ __forceinline__ void gemm_tile(const ushort* __restrict__ A,
                                          const ushort* __restrict__ Bt,
                                          int K, int tileM, int tileN,
                                          ushort* As, ushort* Bs,
                                          f32x4 acc[4][4]) {
    const int t = threadIdx.x;
    const int l = t & 63;
    const int w = __builtin_amdgcn_readfirstlane(t >> 6);
    const int wr = w >> 1, wc = w & 1;
    const int li = l & 15, lg = l >> 4;
    const int lr = l >> 2;
    const int colu = (((l & 3) ^ (lr & 3)) << 3);   // inverse-swizzled src col
    const int swz = (li & 3) << 3;                   // read-side xor

    for (int k0 = 0; k0 < K; k0 += BK) {
        __syncthreads();
        #pragma unroll
        for (int it = 0; it < 2; ++it) {
            const int c2 = it * 4 + w;
            const int row = c2 * 16 + lr;
            glds16(&A[(size_t)(tileM + row) * K + k0 + colu], &As[c2 * 512]);
            glds16(&Bt[(size_t)(tileN + row) * K + k0 + colu], &Bs[c2 * 512]);
        }
        __syncthreads();
        bf16x8 a[4], b[4];
        #pragma unroll
        for (int m = 0; m < 4; ++m)
            a[m] = *(const bf16x8*)&As[(wr * 64 + m * 16 + li) * 32 + ((lg << 3) ^ swz)];
        #pragma unroll
        for (int n = 0; n < 4; ++n)
            b[n] = *(const bf16x8*)&Bs[(wc * 64 + n * 16 + li) * 32 + ((lg << 3) ^ swz)];
        #pragma unroll
        for (int m = 0; m < 4; ++m)
            #pragma unroll
            for (int n = 0; n < 4; ++n)
                acc[m][n] = __builtin_amdgcn_mfma_f32_16x16x32_bf16(a[m], b[n], acc[m][n], 0, 0, 0);
    }
}

// ---------------------------------------------------------------------------
// QKV projection -> q/k/v bf16 in [B,H,N,HD]; Q pre-scaled by
// 0.125*log2(e) (exp2-domain softmax). grid (32, 24)
// ---------------------------------------------------------------------------
#define QSCALE 0.180336880f   // 1/sqrt(64) * log2(e)

__global__ __launch_bounds__(256) void qkv_gemm(const ushort* __restrict__ xb,
                                                const ushort* __restrict__ Wt,
                                                ushort* __restrict__ q,
                                                ushort* __restrict__ k,
                                                ushort* __restrict__ v) {
    __shared__ ushort As[128 * 32];
    __shared__ ushort Bs[128 * 32];
    f32x4 acc[4][4];
    #pragma unroll
    for (int m = 0; m < 4; ++m)
        #pragma unroll
        for (int n = 0; n < 4; ++n)
            acc[m][n] = (f32x4){0.f, 0.f, 0.f, 0.f};

    const int tileM = blockIdx.x * 128;
    const int wsel = blockIdx.y >> 3;
    const int tileN = (blockIdx.y & 7) * 128;
    const ushort* Bmat = Wt + (size_t)wsel * D_ * D_;

    gemm_tile(xb, Bmat, D_, tileM, tileN, As, Bs, acc);

    ushort* out = (wsel == 0) ? q : (wsel == 1) ? k : v;
    const float scale = (wsel == 0) ? QSCALE : 1.0f;
    const int l = threadIdx.x & 63, w = threadIdx.x >> 6;
    const int wr = w >> 1, wc = w & 1;
    const int li = l & 15, lg = l >> 4;
    #pragma unroll
    for (int m = 0; m < 4; ++m)
        #pragma unroll
        for (int n = 0; n < 4; ++n)
            #pragma unroll
            for (int r = 0; r < 4; ++r) {
                int grow = tileM + wr * 64 + m * 16 + lg * 4 + r;
                int gcol = tileN + wc * 64 + n * 16 + li;
                int b = grow >> 11, nn = grow & (N_ - 1);
                int h = gcol >> 6, hd = gcol & 63;
                out[((size_t)(b * H_ + h) * N_ + nn) * HD_ + hd] = bfbits(acc[m][n][r] * scale);
            }
}

// ---------------------------------------------------------------------------
// Output projection: ctx[M][D] * Wo^T + bo -> fp32 out. grid (32, 8)
// ---------------------------------------------------------------------------
__global__ __launch_bounds__(256) void out_gemm(const ushort* __restrict__ ctx,
                                                const ushort* __restrict__ Wt,
                                                const float* __restrict__ bo,
                                                float* __restrict__ outp) {
    __shared__ ushort As[128 * 32];
    __shared__ ushort Bs[128 * 32];
    f32x4 acc[4][4];
    #pragma unroll
    for (int m = 0; m < 4; ++m)
        #pragma unroll
        for (int n = 0; n < 4; ++n)
            acc[m][n] = (f32x4){0.f, 0.f, 0.f, 0.f};

    const int tileM = blockIdx.x * 128;
    const int tileN = blockIdx.y * 128;
    const ushort* Bmat = Wt + (size_t)3 * D_ * D_;   // Wo^T

    gemm_tile(ctx, Bmat, D_, tileM, tileN, As, Bs, acc);

    const int l = threadIdx.x & 63, w = threadIdx.x >> 6;
    const int wr = w >> 1, wc = w & 1;
    const int li = l & 15, lg = l >> 4;
    #pragma unroll
    for (int n = 0; n < 4; ++n) {
        float bias = bo[tileN + wc * 64 + n * 16 + li];
        #pragma unroll
        for (int m = 0; m < 4; ++m)
            #pragma unroll
            for (int r = 0; r < 4; ++r) {
                int grow = tileM + wr * 64 + m * 16 + lg * 4 + r;
                int gcol = tileN + wc * 64 + n * 16 + li;
                outp[(size_t)grow * D_ + gcol] = acc[m][n][r] + bias;
            }
    }
}

// ---------------------------------------------------------------------------
// Barrier-free MFMA causal flash attention, swapped-QK^T form.
//   S^T = mfma(K, Q): lane (li,lg) holds S[k = c*16+lg*4+r][q = li]
//   -> row softmax = in-lane fmax/add tree over 16 vals + 2 shfl_xor (16,32).
// Per-lane scalar m/l (query q=li).  Defer-max THR=8 skips O-rescale.
// K-frags software-pipelined one iteration ahead; V-frags issued at top of
// iteration, consumed after softmax (latency hidden, no barriers).
// Wave-balanced causal: each wave does q-tiles {j, 127-j} (16 rows each) of
// one head -> exactly 33 key-iterations per wave.  grid 512 x 4 waves.
// ---------------------------------------------------------------------------
__global__ __launch_bounds__(256) void attn_fwd(const ushort* __restrict__ q,
                                                const ushort* __restrict__ k,
                                                const ushort* __restrict__ vt,
                                                ushort* __restrict__ ctx) {
    __shared__ ushort Ps[4][16][72];

    const int t = threadIdx.x;
    const int l = t & 63;
    const int w = t >> 6;
    const int li = l & 15, lg = l >> 4;
    const int f = blockIdx.x;                        // 0..511
    const int bh = ((f & 7) << 2) | ((f >> 3) & 3);  // XCD i owns heads 4i..4i+3
    const int j = (f >> 5) * 4 + w;                  // 0..63 per head

    const ushort* Qg = q + (size_t)bh * N_ * HD_;
    const ushort* Kg = k + (size_t)bh * N_ * HD_;
    const ushort* Vg = vt + (size_t)bh * HD_ * N_;
    const int b = bh >> 4, h = bh & 15;

    for (int task = 0; task < 2; ++task) {
        const int qt = (task == 0) ? j : 127 - j;    // 16-row q-tile index
        const int nkb = (qt >> 2) + 1;               // 64-key iterations
        const int qg = qt * 16 + li;                 // this lane's query row

        bf16x8 bq[2];
        #pragma unroll
        for (int tk = 0; tk < 2; ++tk)
            bq[tk] = *(const bf16x8*)&Qg[(size_t)qg * HD_ + tk * 32 + lg * 8];

        f32x4 od[4];
        #pragma unroll
        for (int db = 0; db < 4; ++db) od[db] = (f32x4){0.f, 0.f, 0.f, 0.f};
        float mrun = -INFINITY, lsum = 0.f;

        // preload K fragments for kb = 0
        bf16x8 kf[4][2];
        #pragma unroll
        for (int c = 0; c < 4; ++c)
            #pragma unroll
            for (int tk = 0; tk < 2; ++tk)
                kf[c][tk] = *(const bf16x8*)&Kg[(size_t)(c * 16 + li) * HD_ + tk * 32 + lg * 8];

        #pragma unroll 2
        for (int kb = 0; kb < nkb; ++kb) {
            // issue V fragment loads now; consumed after softmax
            bf16x8 vf[4][2];
            #pragma unroll
            for (int db = 0; db < 4; ++db)
                #pragma unroll
                for (int tj = 0; tj < 2; ++tj)
                    vf[db][tj] = *(const bf16x8*)&Vg[(size_t)(db * 16 + li) * N_ + kb * 64 + tj * 32 + lg * 8];

            // S^T = K * Q^T  (A = K-frag rows, B = Q-frag cols)
            f32x4 st[4];
            #pragma unroll
            for (int c = 0; c < 4; ++c) {
                st[c] = (f32x4){0.f, 0.f, 0.f, 0.f};
                st[c] = __builtin_amdgcn_mfma_f32_16x16x32_bf16(kf[c][0], bq[0], st[c], 0, 0, 0);
                st[c] = __builtin_amdgcn_mfma_f32_16x16x32_bf16(kf[c][1], bq[1], st[c], 0, 0, 0);
            }

            // prefetch K for next iteration (guarded, redundant-safe)
            const int kbn = (kb + 1 < nkb) ? kb + 1 : kb;
            bf16x8 kfn[4][2];
            #pragma unroll
            for (int c = 0; c < 4; ++c)
                #pragma unroll
                for (int tk = 0; tk < 2; ++tk)
                    kfn[c][tk] = *(const bf16x8*)&Kg[(size_t)(kbn * 64 + c * 16 + li) * HD_ + tk * 32 + lg * 8];

            // causal mask (only the diagonal tile needs it)
            const bool lastkb = (kb == (qt >> 2));
            float sv[4][4];
            #pragma unroll
            for (int c = 0; c < 4; ++c)
                #pragma unroll
                for (int r = 0; r < 4; ++r) {
                    const int kgl = kb * 64 + c * 16 + lg * 4 + r;
                    sv[c][r] = (lastkb && kgl > qg) ? -INFINITY : st[c][r];
                }

            // tile row-max: in-lane tree over 16 + 2 cross-lg shfls
            float mx = fmaxf(fmaxf(sv[0][0], sv[0][1]), fmaxf(sv[0][2], sv[0][3]));
            #pragma unroll
            for (int c = 1; c < 4; ++c)
                mx = fmaxf(mx, fmaxf(fmaxf(sv[c][0], sv[c][1]), fmaxf(sv[c][2], sv[c][3])));
            mx = fmaxf(mx, __shfl_xor(mx, 16));
            mx = fmaxf(mx, __shfl_xor(mx, 32));

            // defer-max: rescale only when the max grew by > 2^8
            if (!__all(mx - mrun <= 8.f)) {
                const float mn = fmaxf(mrun, mx);
                const float al = exp2f(mrun - mn);
                lsum *= al;
                mrun = mn;
                float ar[4];
                #pragma unroll
                for (int r = 0; r < 4; ++r) ar[r] = __shfl(al, lg * 4 + r);
                #pragma unroll
                for (int db = 0; db < 4; ++db)
                    #pragma unroll
                    for (int r = 0; r < 4; ++r) od[db][r] *= ar[r];
            }

            // P = exp2(S - m), pack to bf16, stash per-wave in LDS
            float rs = 0.f;
            #pragma unroll
            for (int c = 0; c < 4; ++c) {
                float p0 = exp2f(sv[c][0] - mrun);
                float p1 = exp2f(sv[c][1] - mrun);
                float p2 = exp2f(sv[c][2] - mrun);
                float p3 = exp2f(sv[c][3] - mrun);
                rs += (p0 + p1) + (p2 + p3);
                uint2 pk;
                pk.x = (uint32_t)bfbits(p0) | ((uint32_t)bfbits(p1) << 16);
                pk.y = (uint32_t)bfbits(p2) | ((uint32_t)bfbits(p3) << 16);
                *(uint2*)&Ps[w][li][c * 16 + lg * 4] = pk;
            }
            rs += __shfl_xor(rs, 16);
            rs += __shfl_xor(rs, 32);
            lsum += rs;

            // O += P * V   (A = P rows from LDS, B = V^T frags from regs)
            #pragma unroll
            for (int tj = 0; tj < 2; ++tj) {
                bf16x8 pa = *(const bf16x8*)&Ps[w][li][tj * 32 + lg * 8];
                #pragma unroll
                for (int db = 0; db < 4; ++db)
                    od[db] = __builtin_amdgcn_mfma_f32_16x16x32_bf16(pa, vf[db][tj], od[db], 0, 0, 0);
            }

            #pragma unroll
            for (int c = 0; c < 4; ++c)
                #pragma unroll
                for (int tk = 0; tk < 2; ++tk)
                    kf[c][tk] = kfn[c][tk];
        }

        // epilogue: normalize, write ctx bf16 [B*N][D] heads interleaved
        #pragma unroll
        for (int r = 0; r < 4; ++r) {
            const float inv = 1.f / __shfl(lsum, lg * 4 + r);
            const int grow = qt * 16 + lg * 4 + r;
            #pragma unroll
            for (int db = 0; db < 4; ++db)
                ctx[((size_t)(b * N_ + grow)) * D_ + h * 64 + db * 16 + li] = bfbits(od[db][r] * inv);
        }
    }
}

// ---------------------------------------------------------------------------
extern "C" void kernel_launch(void* const* d_in, const int* in_sizes, int n_in,
                              void* d_out, int out_size, void* d_ws, size_t ws_size,
                              hipStream_t stream) {
    (void)in_sizes; (void)n_in; (void)out_size; (void)ws_size;
    const float* x  = (const float*)d_in[0];
    const float* Wq = (const float*)d_in[1];
    const float* Wk = (const float*)d_in[2];
    const float* Wv = (const float*)d_in[3];
    const float* Wo = (const float*)d_in[4];
    const float* bo = (const float*)d_in[5];
    float* outp = (float*)d_out;

    ushort* xb  = (ushort*)d_ws;                       //  8 MB
    ushort* Wt  = xb + (size_t)M_ * D_;                //  8 MB (4x 1024^2, n-major)
    ushort* qb  = Wt + (size_t)4 * D_ * D_;            //  8 MB [B,H,N,HD]
    ushort* kb  = qb + (size_t)B_ * H_ * N_ * HD_;     //  8 MB [B,H,N,HD]
    ushort* vb  = kb + (size_t)B_ * H_ * N_ * HD_;     //  8 MB [B,H,N,HD]
    ushort* vtb = vb + (size_t)B_ * H_ * N_ * HD_;     //  8 MB [B,H,HD,N]
    ushort* ctx = vtb + (size_t)B_ * H_ * N_ * HD_;    //  8 MB [M][D]

    cvt_x<<<dim3((M_ * D_ / 4) / 256), 256, 0, stream>>>(x, xb);
    cvt_w<<<dim3(32, 32, 4), 256, 0, stream>>>(Wq, Wk, Wv, Wo, Wt);
    qkv_gemm<<<dim3(32, 24), 256, 0, stream>>>(xb, Wt, qb, kb, vb);
    transp_v<<<dim3(32, 32), 256, 0, stream>>>(vb, vtb);
    attn_fwd<<<dim3(512), 256, 0, stream>>>(qb, kb, vtb, ctx);
    out_gemm<<<dim3(32, 8), 256, 0, stream>>>(ctx, Wt, bo, outp);
}

// Round 5
// 124.244 us; speedup vs baseline: 8.4357x; 1.5408x over previous
//
#include <hip/hip_runtime.h>
#include <math.h>
#include <stdint.h>

#define B_ 2
#define N_ 2048
#define D_ 1024
#define H_ 16
#define HD_ 64
#define M_ (B_ * N_)   // 4096

typedef __bf16 bf16x8 __attribute__((ext_vector_type(8)));
typedef float f32x4 __attribute__((ext_vector_type(4)));

__device__ __forceinline__ ushort bfbits(float f) {
    __bf16 h = (__bf16)f;
    return __builtin_bit_cast(ushort, h);
}

// async global->LDS, 16B per lane; LDS dest = wave-uniform base + lane*16
__device__ __forceinline__ void glds16(const ushort* g, ushort* l) {
    __builtin_amdgcn_global_load_lds(
        (const __attribute__((address_space(1))) uint32_t*)g,
        (__attribute__((address_space(3))) uint32_t*)l, 16, 0, 0);
}

// ---------------------------------------------------------------------------
// Convert x (fp32) -> bf16, same layout [M][D]
// ---------------------------------------------------------------------------
__global__ __launch_bounds__(256) void cvt_x(const float* __restrict__ x,
                                             ushort* __restrict__ xb) {
    int i = blockIdx.x * 256 + threadIdx.x;
    float4 v = ((const float4*)x)[i];
    ushort4 o;
    o.x = bfbits(v.x); o.y = bfbits(v.y); o.z = bfbits(v.z); o.w = bfbits(v.w);
    ((ushort4*)xb)[i] = o;
}

// ---------------------------------------------------------------------------
// Convert + transpose weights: W[k][n] fp32 -> Wt[n][k] bf16. grid (32,32,4)
// ---------------------------------------------------------------------------
__global__ __launch_bounds__(256) void cvt_w(const float* __restrict__ W0,
                                             const float* __restrict__ W1,
                                             const float* __restrict__ W2,
                                             const float* __restrict__ W3,
                                             ushort* __restrict__ Wt) {
    __shared__ float T[32][33];
    const float* W = (blockIdx.z == 0) ? W0 : (blockIdx.z == 1) ? W1
                   : (blockIdx.z == 2) ? W2 : W3;
    ushort* out = Wt + (size_t)blockIdx.z * D_ * D_;
    const int t = threadIdx.x;
    const int k0 = blockIdx.x * 32, n0 = blockIdx.y * 32;
    {
        int kl = t >> 3, nl = (t & 7) * 4;
        float4 v = *(const float4*)&W[(size_t)(k0 + kl) * D_ + n0 + nl];
        T[kl][nl] = v.x; T[kl][nl + 1] = v.y; T[kl][nl + 2] = v.z; T[kl][nl + 3] = v.w;
    }
    __syncthreads();
    {
        int nl = t >> 3, k4 = (t & 7) * 4;
        ushort4 o;
        o.x = bfbits(T[k4 + 0][nl]); o.y = bfbits(T[k4 + 1][nl]);
        o.z = bfbits(T[k4 + 2][nl]); o.w = bfbits(T[k4 + 3][nl]);
        *(ushort4*)&out[(size_t)(n0 + nl) * D_ + k0 + k4] = o;
    }
}

// ---------------------------------------------------------------------------
// Transpose V: [B,H,N,HD] -> [B,H,HD,N]. 64x64 tiles. grid (32, 32)
// ---------------------------------------------------------------------------
__global__ __launch_bounds__(256) void transp_v(const ushort* __restrict__ vb,
                                                ushort* __restrict__ vt) {
    __shared__ ushort T[64][72];
    const int t = threadIdx.x;
    const int nt = blockIdx.x, bh = blockIdx.y;
    const ushort* src = vb + ((size_t)bh * N_ + nt * 64) * HD_;
    #pragma unroll
    for (int it = 0; it < 2; ++it) {
        int fi = it * 256 + t;
        int r = fi >> 3, c = (fi & 7) * 8;
        *(uint4*)&T[r][c] = *(const uint4*)&src[(size_t)r * HD_ + c];
    }
    __syncthreads();
    ushort* dst = vt + (size_t)bh * HD_ * N_ + nt * 64;
    #pragma unroll
    for (int it = 0; it < 2; ++it) {
        int fi = it * 256 + t;
        int hd = fi >> 3, n0 = (fi & 7) * 8;
        uint4 o;
        o.x = (uint32_t)T[n0 + 0][hd] | ((uint32_t)T[n0 + 1][hd] << 16);
        o.y = (uint32_t)T[n0 + 2][hd] | ((uint32_t)T[n0 + 3][hd] << 16);
        o.z = (uint32_t)T[n0 + 4][hd] | ((uint32_t)T[n0 + 5][hd] << 16);
        o.w = (uint32_t)T[n0 + 6][hd] | ((uint32_t)T[n0 + 7][hd] << 16);
        *(uint4*)&dst[(size_t)hd * N_ + n0] = o;
    }
}

// ---------------------------------------------------------------------------
// MFMA GEMM mainloop (m97 structure): 128x128 tile, BK=32, linear LDS
// [128][32] bf16 staged via global_load_lds w=16, both-sides XOR swizzle.
// ---------------------------------------------------------------------------
#define BK 32

__device__ __forceinline__ void gemm_tile(const ushort* __restrict__ A,
                                          const ushort* __restrict__ Bt,
                                          int K, int tileM, int tileN,
                                          ushort* As, ushort* Bs,
                                          f32x4 acc[4][4]) {
    const int t = threadIdx.x;
    const int l = t & 63;
    const int w = __builtin_amdgcn_readfirstlane(t >> 6);
    const int wr = w >> 1, wc = w & 1;
    const int li = l & 15, lg = l >> 4;
    const int lr = l >> 2;
    const int colu = (((l & 3) ^ (lr & 3)) << 3);   // inverse-swizzled src col
    const int swz = (li & 3) << 3;                   // read-side xor

    for (int k0 = 0; k0 < K; k0 += BK) {
        __syncthreads();
        #pragma unroll
        for (int it = 0; it < 2; ++it) {
            const int c2 = it * 4 + w;
            const int row = c2 * 16 + lr;
            glds16(&A[(size_t)(tileM + row) * K + k0 + colu], &As[c2 * 512]);
            glds16(&Bt[(size_t)(tileN + row) * K + k0 + colu], &Bs[c2 * 512]);
        }
        __syncthreads();
        bf16x8 a[4], b[4];
        #pragma unroll
        for (int m = 0; m < 4; ++m)
            a[m] = *(const bf16x8*)&As[(wr * 64 + m * 16 + li) * 32 + ((lg << 3) ^ swz)];
        #pragma unroll
        for (int n = 0; n < 4; ++n)
            b[n] = *(const bf16x8*)&Bs[(wc * 64 + n * 16 + li) * 32 + ((lg << 3) ^ swz)];
        #pragma unroll
        for (int m = 0; m < 4; ++m)
            #pragma unroll
            for (int n = 0; n < 4; ++n)
                acc[m][n] = __builtin_amdgcn_mfma_f32_16x16x32_bf16(a[m], b[n], acc[m][n], 0, 0, 0);
    }
}

// ---------------------------------------------------------------------------
// QKV projection -> q/k/v bf16 in [B,H,N,HD]; Q pre-scaled by
// 0.125*log2(e) (exp2-domain softmax). grid (32, 24)
// ---------------------------------------------------------------------------
#define QSCALE 0.180336880f   // 1/sqrt(64) * log2(e)

__global__ __launch_bounds__(256) void qkv_gemm(const ushort* __restrict__ xb,
                                                const ushort* __restrict__ Wt,
                                                ushort* __restrict__ q,
                                                ushort* __restrict__ k,
                                                ushort* __restrict__ v) {
    __shared__ ushort As[128 * 32];
    __shared__ ushort Bs[128 * 32];
    f32x4 acc[4][4];
    #pragma unroll
    for (int m = 0; m < 4; ++m)
        #pragma unroll
        for (int n = 0; n < 4; ++n)
            acc[m][n] = (f32x4){0.f, 0.f, 0.f, 0.f};

    const int tileM = blockIdx.x * 128;
    const int wsel = blockIdx.y >> 3;
    const int tileN = (blockIdx.y & 7) * 128;
    const ushort* Bmat = Wt + (size_t)wsel * D_ * D_;

    gemm_tile(xb, Bmat, D_, tileM, tileN, As, Bs, acc);

    ushort* out = (wsel == 0) ? q : (wsel == 1) ? k : v;
    const float scale = (wsel == 0) ? QSCALE : 1.0f;
    const int l = threadIdx.x & 63, w = threadIdx.x >> 6;
    const int wr = w >> 1, wc = w & 1;
    const int li = l & 15, lg = l >> 4;
    #pragma unroll
    for (int m = 0; m < 4; ++m)
        #pragma unroll
        for (int n = 0; n < 4; ++n)
            #pragma unroll
            for (int r = 0; r < 4; ++r) {
                int grow = tileM + wr * 64 + m * 16 + lg * 4 + r;
                int gcol = tileN + wc * 64 + n * 16 + li;
                int b = grow >> 11, nn = grow & (N_ - 1);
                int h = gcol >> 6, hd = gcol & 63;
                out[((size_t)(b * H_ + h) * N_ + nn) * HD_ + hd] = bfbits(acc[m][n][r] * scale);
            }
}

// ---------------------------------------------------------------------------
// Output projection: ctx[M][D] * Wo^T + bo -> fp32 out. grid (32, 8)
// ---------------------------------------------------------------------------
__global__ __launch_bounds__(256) void out_gemm(const ushort* __restrict__ ctx,
                                                const ushort* __restrict__ Wt,
                                                const float* __restrict__ bo,
                                                float* __restrict__ outp) {
    __shared__ ushort As[128 * 32];
    __shared__ ushort Bs[128 * 32];
    f32x4 acc[4][4];
    #pragma unroll
    for (int m = 0; m < 4; ++m)
        #pragma unroll
        for (int n = 0; n < 4; ++n)
            acc[m][n] = (f32x4){0.f, 0.f, 0.f, 0.f};

    const int tileM = blockIdx.x * 128;
    const int tileN = blockIdx.y * 128;
    const ushort* Bmat = Wt + (size_t)3 * D_ * D_;   // Wo^T

    gemm_tile(ctx, Bmat, D_, tileM, tileN, As, Bs, acc);

    const int l = threadIdx.x & 63, w = threadIdx.x >> 6;
    const int wr = w >> 1, wc = w & 1;
    const int li = l & 15, lg = l >> 4;
    #pragma unroll
    for (int n = 0; n < 4; ++n) {
        float bias = bo[tileN + wc * 64 + n * 16 + li];
        #pragma unroll
        for (int m = 0; m < 4; ++m)
            #pragma unroll
            for (int r = 0; r < 4; ++r) {
                int grow = tileM + wr * 64 + m * 16 + lg * 4 + r;
                int gcol = tileN + wc * 64 + n * 16 + li;
                outp[(size_t)grow * D_ + gcol] = acc[m][n][r] + bias;
            }
    }
}

// ---------------------------------------------------------------------------
// MFMA causal flash attention, swapped-QK^T, LDS-shared K/V tiles.
// Block = 4 waves; block owns q-tile pair {qt, 31-qt} (64 rows each); wave w
// owns rows qt*64 + w*16 .. +15.  Exactly 33 key-iterations per block.
// K tile [64 keys][64 hd] and V^T tile [64 hd][64 keys] staged in LDS via
// global_load_lds w=16, double-buffered, shared by all 4 waves (L2 traffic
// /4 vs per-wave fragment loads).  128B rows -> slot^(row&7) XOR swizzle,
// applied both-sides (inverse-swizzled global src, swizzled ds_read).
// 2-phase pipeline: stage kb+1 at top of iter, compute kb from LDS, one
// __syncthreads() per iter (its vmcnt(0) drain lands the prefetch).
//   S^T = mfma(K, Q): lane (li,lg) holds S[k=c*16+lg*4+r][q=li];
//   softmax = in-lane tree + 2 shfl_xor; defer-max THR=8.
// grid 512; head = XCD-swizzled f&31, pair = f>>5.
// ---------------------------------------------------------------------------
__global__ __launch_bounds__(256) void attn_fwd(const ushort* __restrict__ q,
                                                const ushort* __restrict__ k,
                                                const ushort* __restrict__ vt,
                                                ushort* __restrict__ ctx) {
    __shared__ ushort Ks[2][64 * 64];   // [buf][row*64 + slot*8], swizzled
    __shared__ ushort Vs[2][64 * 64];
    __shared__ ushort Ps[4][16][72];

    const int t = threadIdx.x;
    const int l = t & 63;
    const int w = __builtin_amdgcn_readfirstlane(t >> 6);
    const int li = l & 15, lg = l >> 4;
    const int f = blockIdx.x;                        // 0..511
    const int bh = ((f & 7) << 2) | ((f >> 3) & 3);  // XCD i owns heads 4i..4i+3
    const int pj = f >> 5;                           // 0..15 pair index

    const ushort* Qg = q + (size_t)bh * N_ * HD_;
    const ushort* Kg = k + (size_t)bh * N_ * HD_;
    const ushort* Vg = vt + (size_t)bh * HD_ * N_;
    const int b = bh >> 4, h = bh & 15;

    // staging geometry: lane l covers row r8 = l>>3 of an 8-row segment,
    // LDS slot l&7; inverse-swizzled source slot = (l&7) ^ (row&7), row&7 = r8
    const int r8 = l >> 3;
    const int soff = ((l & 7) ^ r8) * 8;             // source slot offset (ushorts)
    const int rswz = li & 7;                         // read-side row xor

    for (int task = 0; task < 2; ++task) {
        const int qt = (task == 0) ? pj : 31 - pj;   // 64-row q-tile index
        const int nkb = qt + 1;                      // 64-key iterations
        const int qb64 = qt * 64 + w * 16;
        const int qg = qb64 + li;                    // this lane's query row

        bf16x8 bq[2];
        #pragma unroll
        for (int tk = 0; tk < 2; ++tk)
            bq[tk] = *(const bf16x8*)&Qg[(size_t)qg * HD_ + tk * 32 + lg * 8];

        f32x4 od[4];
        #pragma unroll
        for (int db = 0; db < 4; ++db) od[db] = (f32x4){0.f, 0.f, 0.f, 0.f};
        float mrun = -INFINITY, lsum = 0.f;

        // stage tile kb=0 into buf 0: wave w stages segments {w, w+4} of K and V
        #pragma unroll
        for (int i = 0; i < 2; ++i) {
            const int seg = w + i * 4;
            const int row = seg * 8 + r8;
            glds16(&Kg[(size_t)row * HD_ + soff], &Ks[0][seg * 512]);
            glds16(&Vg[(size_t)row * N_ + soff], &Vs[0][seg * 512]);
        }
        __syncthreads();

        int cur = 0;
        for (int kb = 0; kb < nkb; ++kb) {
            // issue next-tile stage (lands by the end-of-iter barrier)
            if (kb + 1 < nkb) {
                #pragma unroll
                for (int i = 0; i < 2; ++i) {
                    const int seg = w + i * 4;
                    const int row = seg * 8 + r8;
                    glds16(&Kg[(size_t)((kb + 1) * 64 + row) * HD_ + soff], &Ks[cur ^ 1][seg * 512]);
                    glds16(&Vg[(size_t)row * N_ + (kb + 1) * 64 + soff], &Vs[cur ^ 1][seg * 512]);
                }
            }

            // S^T = K * Q^T from LDS (swizzled reads, conflict-free)
            f32x4 st[4];
            #pragma unroll
            for (int c = 0; c < 4; ++c) {
                st[c] = (f32x4){0.f, 0.f, 0.f, 0.f};
                #pragma unroll
                for (int tk = 0; tk < 2; ++tk) {
                    bf16x8 kf = *(const bf16x8*)&Ks[cur][(c * 16 + li) * 64 + (((tk * 4 + lg) ^ rswz) * 8)];
                    st[c] = __builtin_amdgcn_mfma_f32_16x16x32_bf16(kf, bq[tk], st[c], 0, 0, 0);
                }
            }

            // causal mask (diagonal tile only)
            const bool lastkb = (kb == qt);
            float sv[4][4];
            #pragma unroll
            for (int c = 0; c < 4; ++c)
                #pragma unroll
                for (int r = 0; r < 4; ++r) {
                    const int kgl = kb * 64 + c * 16 + lg * 4 + r;
                    sv[c][r] = (lastkb && kgl > qg) ? -INFINITY : st[c][r];
                }

            // tile row-max: in-lane tree over 16 + 2 cross-lg shfls
            float mx = fmaxf(fmaxf(sv[0][0], sv[0][1]), fmaxf(sv[0][2], sv[0][3]));
            #pragma unroll
            for (int c = 1; c < 4; ++c)
                mx = fmaxf(mx, fmaxf(fmaxf(sv[c][0], sv[c][1]), fmaxf(sv[c][2], sv[c][3])));
            mx = fmaxf(mx, __shfl_xor(mx, 16));
            mx = fmaxf(mx, __shfl_xor(mx, 32));

            // defer-max: rescale only when the max grew by > 2^8
            if (!__all(mx - mrun <= 8.f)) {
                const float mn = fmaxf(mrun, mx);
                const float al = exp2f(mrun - mn);
                lsum *= al;
                mrun = mn;
                float ar[4];
                #pragma unroll
                for (int r = 0; r < 4; ++r) ar[r] = __shfl(al, lg * 4 + r);
                #pragma unroll
                for (int db = 0; db < 4; ++db)
                    #pragma unroll
                    for (int r = 0; r < 4; ++r) od[db][r] *= ar[r];
            }

            // P = exp2(S - m), pack bf16, stash per-wave in LDS
            float rs = 0.f;
            #pragma unroll
            for (int c = 0; c < 4; ++c) {
                float p0 = exp2f(sv[c][0] - mrun);
                float p1 = exp2f(sv[c][1] - mrun);
                float p2 = exp2f(sv[c][2] - mrun);
                float p3 = exp2f(sv[c][3] - mrun);
                rs += (p0 + p1) + (p2 + p3);
                uint2 pk;
                pk.x = (uint32_t)bfbits(p0) | ((uint32_t)bfbits(p1) << 16);
                pk.y = (uint32_t)bfbits(p2) | ((uint32_t)bfbits(p3) << 16);
                *(uint2*)&Ps[w][li][c * 16 + lg * 4] = pk;
            }
            rs += __shfl_xor(rs, 16);
            rs += __shfl_xor(rs, 32);
            lsum += rs;

            // O += P * V (A = P rows from LDS, B = V^T rows from LDS)
            #pragma unroll
            for (int tj = 0; tj < 2; ++tj) {
                bf16x8 pa = *(const bf16x8*)&Ps[w][li][tj * 32 + lg * 8];
                #pragma unroll
                for (int db = 0; db < 4; ++db) {
                    bf16x8 bv = *(const bf16x8*)&Vs[cur][(db * 16 + li) * 64 + (((tj * 4 + lg) ^ rswz) * 8)];
                    od[db] = __builtin_amdgcn_mfma_f32_16x16x32_bf16(pa, bv, od[db], 0, 0, 0);
                }
            }

            __syncthreads();   // all reads of buf[cur] done + prefetch landed
            cur ^= 1;
        }

        // epilogue: normalize, write ctx bf16 [B*N][D] heads interleaved
        #pragma unroll
        for (int r = 0; r < 4; ++r) {
            const float inv = 1.f / __shfl(lsum, lg * 4 + r);
            const int grow = qb64 + lg * 4 + r;
            #pragma unroll
            for (int db = 0; db < 4; ++db)
                ctx[((size_t)(b * N_ + grow)) * D_ + h * 64 + db * 16 + li] = bfbits(od[db][r] * inv);
        }
    }
}

// ---------------------------------------------------------------------------
extern "C" void kernel_launch(void* const* d_in, const int* in_sizes, int n_in,
                              void* d_out, int out_size, void* d_ws, size_t ws_size,
                              hipStream_t stream) {
    (void)in_sizes; (void)n_in; (void)out_size; (void)ws_size;
    const float* x  = (const float*)d_in[0];
    const float* Wq = (const float*)d_in[1];
    const float* Wk = (const float*)d_in[2];
    const float* Wv = (const float*)d_in[3];
    const float* Wo = (const float*)d_in[4];
    const float* bo = (const float*)d_in[5];
    float* outp = (float*)d_out;

    ushort* xb  = (ushort*)d_ws;                       //  8 MB
    ushort* Wt  = xb + (size_t)M_ * D_;                //  8 MB (4x 1024^2, n-major)
    ushort* qb  = Wt + (size_t)4 * D_ * D_;            //  8 MB [B,H,N,HD]
    ushort* kb  = qb + (size_t)B_ * H_ * N_ * HD_;     //  8 MB [B,H,N,HD]
    ushort* vb  = kb + (size_t)B_ * H_ * N_ * HD_;     //  8 MB [B,H,N,HD]
    ushort* vtb = vb + (size_t)B_ * H_ * N_ * HD_;     //  8 MB [B,H,HD,N]
    ushort* ctx = vtb + (size_t)B_ * H_ * N_ * HD_;    //  8 MB [M][D]

    cvt_x<<<dim3((M_ * D_ / 4) / 256), 256, 0, stream>>>(x, xb);
    cvt_w<<<dim3(32, 32, 4), 256, 0, stream>>>(Wq, Wk, Wv, Wo, Wt);
    qkv_gemm<<<dim3(32, 24), 256, 0, stream>>>(xb, Wt, qb, kb, vb);
    transp_v<<<dim3(32, 32), 256, 0, stream>>>(vb, vtb);
    attn_fwd<<<dim3(512), 256, 0, stream>>>(qb, kb, vtb, ctx);
    out_gemm<<<dim3(32, 8), 256, 0, stream>>>(ctx, Wt, bo, outp);
}

// Round 6
// 119.171 us; speedup vs baseline: 8.7948x; 1.0426x over previous
//
#include <hip/hip_runtime.h>
#include <math.h>
#include <stdint.h>

#define B_ 2
#define N_ 2048
#define D_ 1024
#define H_ 16
#define HD_ 64
#define M_ (B_ * N_)   // 4096

typedef __bf16 bf16x8 __attribute__((ext_vector_type(8)));
typedef float f32x4 __attribute__((ext_vector_type(4)));

__device__ __forceinline__ ushort bfbits(float f) {
    __bf16 h = (__bf16)f;
    return __builtin_bit_cast(ushort, h);
}

// async global->LDS, 16B per lane; LDS dest = wave-uniform base + lane*16
__device__ __forceinline__ void glds16(const ushort* g, ushort* l) {
    __builtin_amdgcn_global_load_lds(
        (const __attribute__((address_space(1))) uint32_t*)g,
        (__attribute__((address_space(3))) uint32_t*)l, 16, 0, 0);
}

// ---------------------------------------------------------------------------
// Convert x (fp32) -> bf16, same layout [M][D]
// ---------------------------------------------------------------------------
__global__ __launch_bounds__(256) void cvt_x(const float* __restrict__ x,
                                             ushort* __restrict__ xb) {
    int i = blockIdx.x * 256 + threadIdx.x;
    float4 v = ((const float4*)x)[i];
    ushort4 o;
    o.x = bfbits(v.x); o.y = bfbits(v.y); o.z = bfbits(v.z); o.w = bfbits(v.w);
    ((ushort4*)xb)[i] = o;
}

// ---------------------------------------------------------------------------
// Convert + transpose weights: W[k][n] fp32 -> Wt[n][k] bf16. grid (32,32,4)
// ---------------------------------------------------------------------------
__global__ __launch_bounds__(256) void cvt_w(const float* __restrict__ W0,
                                             const float* __restrict__ W1,
                                             const float* __restrict__ W2,
                                             const float* __restrict__ W3,
                                             ushort* __restrict__ Wt) {
    __shared__ float T[32][33];
    const float* W = (blockIdx.z == 0) ? W0 : (blockIdx.z == 1) ? W1
                   : (blockIdx.z == 2) ? W2 : W3;
    ushort* out = Wt + (size_t)blockIdx.z * D_ * D_;
    const int t = threadIdx.x;
    const int k0 = blockIdx.x * 32, n0 = blockIdx.y * 32;
    {
        int kl = t >> 3, nl = (t & 7) * 4;
        float4 v = *(const float4*)&W[(size_t)(k0 + kl) * D_ + n0 + nl];
        T[kl][nl] = v.x; T[kl][nl + 1] = v.y; T[kl][nl + 2] = v.z; T[kl][nl + 3] = v.w;
    }
    __syncthreads();
    {
        int nl = t >> 3, k4 = (t & 7) * 4;
        ushort4 o;
        o.x = bfbits(T[k4 + 0][nl]); o.y = bfbits(T[k4 + 1][nl]);
        o.z = bfbits(T[k4 + 2][nl]); o.w = bfbits(T[k4 + 3][nl]);
        *(ushort4*)&out[(size_t)(n0 + nl) * D_ + k0 + k4] = o;
    }
}

// ---------------------------------------------------------------------------
// Transpose V: [B,H,N,HD] -> [B,H,HD,N]. 64x64 tiles. grid (32, 32)
// ---------------------------------------------------------------------------
__global__ __launch_bounds__(256) void transp_v(const ushort* __restrict__ vb,
                                                ushort* __restrict__ vt) {
    __shared__ ushort T[64][72];
    const int t = threadIdx.x;
    const int nt = blockIdx.x, bh = blockIdx.y;
    const ushort* src = vb + ((size_t)bh * N_ + nt * 64) * HD_;
    #pragma unroll
    for (int it = 0; it < 2; ++it) {
        int fi = it * 256 + t;
        int r = fi >> 3, c = (fi & 7) * 8;
        *(uint4*)&T[r][c] = *(const uint4*)&src[(size_t)r * HD_ + c];
    }
    __syncthreads();
    ushort* dst = vt + (size_t)bh * HD_ * N_ + nt * 64;
    #pragma unroll
    for (int it = 0; it < 2; ++it) {
        int fi = it * 256 + t;
        int hd = fi >> 3, n0 = (fi & 7) * 8;
        uint4 o;
        o.x = (uint32_t)T[n0 + 0][hd] | ((uint32_t)T[n0 + 1][hd] << 16);
        o.y = (uint32_t)T[n0 + 2][hd] | ((uint32_t)T[n0 + 3][hd] << 16);
        o.z = (uint32_t)T[n0 + 4][hd] | ((uint32_t)T[n0 + 5][hd] << 16);
        o.w = (uint32_t)T[n0 + 6][hd] | ((uint32_t)T[n0 + 7][hd] << 16);
        *(uint4*)&dst[(size_t)hd * N_ + n0] = o;
    }
}

// ---------------------------------------------------------------------------
// MFMA GEMM mainloop (m97 structure): 128x128 tile, BK=32, linear LDS
// [128][32] bf16 staged via global_load_lds w=16, both-sides XOR swizzle.
// ---------------------------------------------------------------------------
#define BK 32

__device__ __forceinline__ void gemm_tile(const ushort* __restrict__ A,
                                          const ushort* __restrict__ Bt,
                                          int K, int tileM, int tileN,
                                          ushort* As, ushort* Bs,
                                          f32x4 acc[4][4]) {
    const int t = threadIdx.x;
    const int l = t & 63;
    const int w = __builtin_amdgcn_readfirstlane(t >> 6);
    const int wr = w >> 1, wc = w & 1;
    const int li = l & 15, lg = l >> 4;
    const int lr = l >> 2;
    const int colu = (((l & 3) ^ (lr & 3)) << 3);   // inverse-swizzled src col
    const int swz = (li & 3) << 3;                   // read-side xor

    for (int k0 = 0; k0 < K; k0 += BK) {
        __syncthreads();
        #pragma unroll
        for (int it = 0; it < 2; ++it) {
            const int c2 = it * 4 + w;
            const int row = c2 * 16 + lr;
            glds16(&A[(size_t)(tileM + row) * K + k0 + colu], &As[c2 * 512]);
            glds16(&Bt[(size_t)(tileN + row) * K + k0 + colu], &Bs[c2 * 512]);
        }
        __syncthreads();
        bf16x8 a[4], b[4];
        #pragma unroll
        for (int m = 0; m < 4; ++m)
            a[m] = *(const bf16x8*)&As[(wr * 64 + m * 16 + li) * 32 + ((lg << 3) ^ swz)];
        #pragma unroll
        for (int n = 0; n < 4; ++n)
            b[n] = *(const bf16x8*)&Bs[(wc * 64 + n * 16 + li) * 32 + ((lg << 3) ^ swz)];
        #pragma unroll
        for (int m = 0; m < 4; ++m)
            #pragma unroll
            for (int n = 0; n < 4; ++n)
                acc[m][n] = __builtin_amdgcn_mfma_f32_16x16x32_bf16(a[m], b[n], acc[m][n], 0, 0, 0);
    }
}

// ---------------------------------------------------------------------------
// QKV projection -> q/k/v bf16 in [B,H,N,HD]; Q pre-scaled by
// 0.125*log2(e) (exp2-domain softmax). grid (32, 24)
// ---------------------------------------------------------------------------
#define QSCALE 0.180336880f   // 1/sqrt(64) * log2(e)

__global__ __launch_bounds__(256) void qkv_gemm(const ushort* __restrict__ xb,
                                                const ushort* __restrict__ Wt,
                                                ushort* __restrict__ q,
                                                ushort* __restrict__ k,
                                                ushort* __restrict__ v) {
    __shared__ ushort As[128 * 32];
    __shared__ ushort Bs[128 * 32];
    f32x4 acc[4][4];
    #pragma unroll
    for (int m = 0; m < 4; ++m)
        #pragma unroll
        for (int n = 0; n < 4; ++n)
            acc[m][n] = (f32x4){0.f, 0.f, 0.f, 0.f};

    const int tileM = blockIdx.x * 128;
    const int wsel = blockIdx.y >> 3;
    const int tileN = (blockIdx.y & 7) * 128;
    const ushort* Bmat = Wt + (size_t)wsel * D_ * D_;

    gemm_tile(xb, Bmat, D_, tileM, tileN, As, Bs, acc);

    ushort* out = (wsel == 0) ? q : (wsel == 1) ? k : v;
    const float scale = (wsel == 0) ? QSCALE : 1.0f;
    const int l = threadIdx.x & 63, w = threadIdx.x >> 6;
    const int wr = w >> 1, wc = w & 1;
    const int li = l & 15, lg = l >> 4;
    #pragma unroll
    for (int m = 0; m < 4; ++m)
        #pragma unroll
        for (int n = 0; n < 4; ++n)
            #pragma unroll
            for (int r = 0; r < 4; ++r) {
                int grow = tileM + wr * 64 + m * 16 + lg * 4 + r;
                int gcol = tileN + wc * 64 + n * 16 + li;
                int b = grow >> 11, nn = grow & (N_ - 1);
                int h = gcol >> 6, hd = gcol & 63;
                out[((size_t)(b * H_ + h) * N_ + nn) * HD_ + hd] = bfbits(acc[m][n][r] * scale);
            }
}

// ---------------------------------------------------------------------------
// Output projection: ctx[M][D] * Wo^T + bo -> fp32 out. grid (32, 8)
// ---------------------------------------------------------------------------
__global__ __launch_bounds__(256) void out_gemm(const ushort* __restrict__ ctx,
                                                const ushort* __restrict__ Wt,
                                                const float* __restrict__ bo,
                                                float* __restrict__ outp) {
    __shared__ ushort As[128 * 32];
    __shared__ ushort Bs[128 * 32];
    f32x4 acc[4][4];
    #pragma unroll
    for (int m = 0; m < 4; ++m)
        #pragma unroll
        for (int n = 0; n < 4; ++n)
            acc[m][n] = (f32x4){0.f, 0.f, 0.f, 0.f};

    const int tileM = blockIdx.x * 128;
    const int tileN = blockIdx.y * 128;
    const ushort* Bmat = Wt + (size_t)3 * D_ * D_;   // Wo^T

    gemm_tile(ctx, Bmat, D_, tileM, tileN, As, Bs, acc);

    const int l = threadIdx.x & 63, w = threadIdx.x >> 6;
    const int wr = w >> 1, wc = w & 1;
    const int li = l & 15, lg = l >> 4;
    #pragma unroll
    for (int n = 0; n < 4; ++n) {
        float bias = bo[tileN + wc * 64 + n * 16 + li];
        #pragma unroll
        for (int m = 0; m < 4; ++m)
            #pragma unroll
            for (int r = 0; r < 4; ++r) {
                int grow = tileM + wr * 64 + m * 16 + lg * 4 + r;
                int gcol = tileN + wc * 64 + n * 16 + li;
                outp[(size_t)grow * D_ + gcol] = acc[m][n][r] + bias;
            }
    }
}

// ---------------------------------------------------------------------------
// MFMA causal flash attention, swapped-QK^T, LDS-shared K/V tiles.
// One 64-row q-tile per block (grid 1024, work-descending so qt=31 blocks
// launch first; 3 blocks/CU at 42KB LDS -> dynamic load balance).
// Main loop is UNMASKED (no causal VALU); the diagonal tile is a separate
// final masked step.  K/V staged via global_load_lds w=16, double-buffered,
// both-sides XOR swizzle (slot^(row&7)); one __syncthreads per iteration.
//   S^T = mfma(K, Q): lane (li,lg) holds S[k=c*16+lg*4+r][q=li];
//   softmax in-lane tree + 2 shfl_xor; defer-max THR=8.
// ---------------------------------------------------------------------------
#define ATTN_STEP(CUR, KB, MASKED)                                             \
{                                                                              \
    const ushort* Kb_ = Ks[CUR];                                               \
    const ushort* Vb_ = Vs[CUR];                                               \
    f32x4 st[4];                                                               \
    _Pragma("unroll")                                                          \
    for (int c = 0; c < 4; ++c) {                                              \
        st[c] = (f32x4){0.f, 0.f, 0.f, 0.f};                                   \
        _Pragma("unroll")                                                      \
        for (int tk = 0; tk < 2; ++tk) {                                       \
            bf16x8 kf = *(const bf16x8*)&Kb_[(c * 16 + li) * 64 +              \
                                             (((tk * 4 + lg) ^ rswz) * 8)];    \
            st[c] = __builtin_amdgcn_mfma_f32_16x16x32_bf16(kf, bq[tk], st[c], 0, 0, 0); \
        }                                                                      \
    }                                                                          \
    if (MASKED) {                                                              \
        _Pragma("unroll")                                                      \
        for (int c = 0; c < 4; ++c)                                            \
            _Pragma("unroll")                                                  \
            for (int r = 0; r < 4; ++r) {                                      \
                const int kgl = (KB) * 64 + c * 16 + lg * 4 + r;               \
                if (kgl > qg) st[c][r] = -INFINITY;                            \
            }                                                                  \
    }                                                                          \
    float mx = fmaxf(fmaxf(st[0][0], st[0][1]), fmaxf(st[0][2], st[0][3]));    \
    _Pragma("unroll")                                                          \
    for (int c = 1; c < 4; ++c)                                                \
        mx = fmaxf(mx, fmaxf(fmaxf(st[c][0], st[c][1]), fmaxf(st[c][2], st[c][3]))); \
    mx = fmaxf(mx, __shfl_xor(mx, 16));                                        \
    mx = fmaxf(mx, __shfl_xor(mx, 32));                                        \
    if (!__all(mx - mrun <= 8.f)) {                                            \
        const float mn = fmaxf(mrun, mx);                                      \
        const float al = exp2f(mrun - mn);                                     \
        lsum *= al;                                                            \
        mrun = mn;                                                             \
        float ar[4];                                                           \
        _Pragma("unroll")                                                      \
        for (int r = 0; r < 4; ++r) ar[r] = __shfl(al, lg * 4 + r);            \
        _Pragma("unroll")                                                      \
        for (int db = 0; db < 4; ++db)                                         \
            _Pragma("unroll")                                                  \
            for (int r = 0; r < 4; ++r) od[db][r] *= ar[r];                    \
    }                                                                          \
    float rs = 0.f;                                                            \
    _Pragma("unroll")                                                          \
    for (int c = 0; c < 4; ++c) {                                              \
        float p0 = exp2f(st[c][0] - mrun);                                     \
        float p1 = exp2f(st[c][1] - mrun);                                     \
        float p2 = exp2f(st[c][2] - mrun);                                     \
        float p3 = exp2f(st[c][3] - mrun);                                     \
        rs += (p0 + p1) + (p2 + p3);                                           \
        uint2 pk;                                                              \
        pk.x = (uint32_t)bfbits(p0) | ((uint32_t)bfbits(p1) << 16);            \
        pk.y = (uint32_t)bfbits(p2) | ((uint32_t)bfbits(p3) << 16);            \
        *(uint2*)&Ps[w][li][c * 16 + lg * 4] = pk;                             \
    }                                                                          \
    rs += __shfl_xor(rs, 16);                                                  \
    rs += __shfl_xor(rs, 32);                                                  \
    lsum += rs;                                                                \
    _Pragma("unroll")                                                          \
    for (int tj = 0; tj < 2; ++tj) {                                           \
        bf16x8 pa = *(const bf16x8*)&Ps[w][li][tj * 32 + lg * 8];              \
        _Pragma("unroll")                                                      \
        for (int db = 0; db < 4; ++db) {                                       \
            bf16x8 bv = *(const bf16x8*)&Vb_[(db * 16 + li) * 64 +             \
                                             (((tj * 4 + lg) ^ rswz) * 8)];    \
            od[db] = __builtin_amdgcn_mfma_f32_16x16x32_bf16(pa, bv, od[db], 0, 0, 0); \
        }                                                                      \
    }                                                                          \
}

__global__ __launch_bounds__(256) void attn_fwd(const ushort* __restrict__ q,
                                                const ushort* __restrict__ k,
                                                const ushort* __restrict__ vt,
                                                ushort* __restrict__ ctx) {
    __shared__ ushort Ks[2][64 * 64];   // [buf][row*64 + slot*8], swizzled
    __shared__ ushort Vs[2][64 * 64];
    __shared__ ushort Ps[4][16][72];

    const int t = threadIdx.x;
    const int l = t & 63;
    const int w = __builtin_amdgcn_readfirstlane(t >> 6);
    const int li = l & 15, lg = l >> 4;
    const int f = blockIdx.x;                        // 0..1023
    const int bh = ((f & 7) << 2) | ((f >> 3) & 3);  // XCD i owns heads 4i..4i+3
    const int qt = 31 - (f >> 5);                    // heavy q-tiles first

    const ushort* Qg = q + (size_t)bh * N_ * HD_;
    const ushort* Kg = k + (size_t)bh * N_ * HD_;
    const ushort* Vg = vt + (size_t)bh * HD_ * N_;
    const int b = bh >> 4, h = bh & 15;

    // staging geometry: lane l covers row r8 = l>>3 of an 8-row segment,
    // LDS slot l&7; inverse-swizzled source slot = (l&7) ^ (row&7)
    const int r8 = l >> 3;
    const int soff = ((l & 7) ^ r8) * 8;             // source slot offset
    const int rswz = li & 7;                         // read-side row xor

    const int qb64 = qt * 64 + w * 16;
    const int qg = qb64 + li;                        // this lane's query row

    bf16x8 bq[2];
    #pragma unroll
    for (int tk = 0; tk < 2; ++tk)
        bq[tk] = *(const bf16x8*)&Qg[(size_t)qg * HD_ + tk * 32 + lg * 8];

    f32x4 od[4];
    #pragma unroll
    for (int db = 0; db < 4; ++db) od[db] = (f32x4){0.f, 0.f, 0.f, 0.f};
    float mrun = -INFINITY, lsum = 0.f;

    // stage tile kb=0 into buf 0: wave w stages segments {w, w+4} of K and V
    #pragma unroll
    for (int i = 0; i < 2; ++i) {
        const int seg = w + i * 4;
        const int row = seg * 8 + r8;
        glds16(&Kg[(size_t)row * HD_ + soff], &Ks[0][seg * 512]);
        glds16(&Vg[(size_t)row * N_ + soff], &Vs[0][seg * 512]);
    }
    __syncthreads();

    int cur = 0;
    for (int kb = 0; kb < qt; ++kb) {            // all iterations unmasked
        // issue next-tile stage (always valid: kb+1 <= qt)
        #pragma unroll
        for (int i = 0; i < 2; ++i) {
            const int seg = w + i * 4;
            const int row = seg * 8 + r8;
            glds16(&Kg[(size_t)((kb + 1) * 64 + row) * HD_ + soff], &Ks[cur ^ 1][seg * 512]);
            glds16(&Vg[(size_t)row * N_ + (kb + 1) * 64 + soff], &Vs[cur ^ 1][seg * 512]);
        }
        ATTN_STEP(cur, kb, false)
        __syncthreads();   // reads of buf[cur] done + prefetch landed
        cur ^= 1;
    }
    // diagonal tile (masked), no prefetch
    ATTN_STEP(cur, qt, true)

    // epilogue: normalize, write ctx bf16 [B*N][D] heads interleaved
    #pragma unroll
    for (int r = 0; r < 4; ++r) {
        const float inv = 1.f / __shfl(lsum, lg * 4 + r);
        const int grow = qb64 + lg * 4 + r;
        #pragma unroll
        for (int db = 0; db < 4; ++db)
            ctx[((size_t)(b * N_ + grow)) * D_ + h * 64 + db * 16 + li] = bfbits(od[db][r] * inv);
    }
}

// ---------------------------------------------------------------------------
extern "C" void kernel_launch(void* const* d_in, const int* in_sizes, int n_in,
                              void* d_out, int out_size, void* d_ws, size_t ws_size,
                              hipStream_t stream) {
    (void)in_sizes; (void)n_in; (void)out_size; (void)ws_size;
    const float* x  = (const float*)d_in[0];
    const float* Wq = (const float*)d_in[1];
    const float* Wk = (const float*)d_in[2];
    const float* Wv = (const float*)d_in[3];
    const float* Wo = (const float*)d_in[4];
    const float* bo = (const float*)d_in[5];
    float* outp = (float*)d_out;

    ushort* xb  = (ushort*)d_ws;                       //  8 MB
    ushort* Wt  = xb + (size_t)M_ * D_;                //  8 MB (4x 1024^2, n-major)
    ushort* qb  = Wt + (size_t)4 * D_ * D_;            //  8 MB [B,H,N,HD]
    ushort* kb  = qb + (size_t)B_ * H_ * N_ * HD_;     //  8 MB [B,H,N,HD]
    ushort* vb  = kb + (size_t)B_ * H_ * N_ * HD_;     //  8 MB [B,H,N,HD]
    ushort* vtb = vb + (size_t)B_ * H_ * N_ * HD_;     //  8 MB [B,H,HD,N]
    ushort* ctx = vtb + (size_t)B_ * H_ * N_ * HD_;    //  8 MB [M][D]

    cvt_x<<<dim3((M_ * D_ / 4) / 256), 256, 0, stream>>>(x, xb);
    cvt_w<<<dim3(32, 32, 4), 256, 0, stream>>>(Wq, Wk, Wv, Wo, Wt);
    qkv_gemm<<<dim3(32, 24), 256, 0, stream>>>(xb, Wt, qb, kb, vb);
    transp_v<<<dim3(32, 32), 256, 0, stream>>>(vb, vtb);
    attn_fwd<<<dim3(1024), 256, 0, stream>>>(qb, kb, vtb, ctx);
    out_gemm<<<dim3(32, 8), 256, 0, stream>>>(ctx, Wt, bo, outp);
}